// Round 14
// baseline (208.940 us; speedup 1.0000x reference)
//
#include <hip/hip_runtime.h>
#include <hip/hip_fp16.h>
#include <math.h>

#define N_NODES 100000
#define N_EDGES 6400000
#define F_IN 36
#define HID 8
#define NCLS 2
#define NEG_SLOPE 0.2f

#define COARSE 256                        // nodes per coarse bucket (dst >> 8)
#define NBC 391                           // ceil(N_NODES/256)
#define CAPC 18432                        // max edges per coarse bucket (mean ~16368, +16 sigma)
#define CHUNK 4096                        // edges staged per kA block
#define NSTG ((N_EDGES + CHUNK - 1) / CHUNK)   // 1563
#define SHIFT1 8.0f                       // softmax shift (softmax is shift-invariant)
#define SHIFT2 16.0f

// rec1: 32B-aligned record per node: [0]=s1s f32, [1]=s1d f32, [2..5]=h0..h7 fp16 pairs, [6..7]=pad

static __device__ __forceinline__ unsigned pack2h(float a, float b) {
    __half2 h = __float22half2_rn(make_float2(a, b));
    return *reinterpret_cast<unsigned*>(&h);
}
static __device__ __forceinline__ float2 unpack2h(unsigned u) {
    __half2 h = *reinterpret_cast<__half2*>(&u);
    return __half22float2(h);
}

// ------- K0: per-node rec1 (packed)  +  fused dst histogram ----------------
__global__ __launch_bounds__(256) void k0_node(
    const float* __restrict__ x, const float* __restrict__ W1,
    const float* __restrict__ a1s_g, const float* __restrict__ a1d_g,
    const int* __restrict__ dst,
    unsigned* __restrict__ rec1, int* __restrict__ ccnt)
{
    __shared__ float sW[F_IN * HID];
    __shared__ float sas[HID], sad[HID];
    __shared__ int lh[NBC];
    int tid = threadIdx.x;
    for (int i = tid; i < F_IN * HID; i += 256) sW[i] = W1[i];
    for (int i = tid; i < NBC; i += 256) lh[i] = 0;
    if (tid < HID) { sas[tid] = a1s_g[tid]; sad[tid] = a1d_g[tid]; }
    __syncthreads();

    int n = blockIdx.x * 256 + tid;
    if (n < N_NODES) {
        const float4* xp = (const float4*)(x + (size_t)n * F_IN);
        float h[HID];
#pragma unroll
        for (int f = 0; f < HID; ++f) h[f] = 0.f;
#pragma unroll
        for (int q = 0; q < F_IN / 4; ++q) {
            float4 v = xp[q];
            float vs[4] = {v.x, v.y, v.z, v.w};
#pragma unroll
            for (int j = 0; j < 4; ++j) {
                int k = q * 4 + j;
#pragma unroll
                for (int f = 0; f < HID; ++f) h[f] = fmaf(vs[j], sW[k * HID + f], h[f]);
            }
        }
        float ss = 0.f, sd = 0.f;
#pragma unroll
        for (int f = 0; f < HID; ++f) { ss = fmaf(h[f], sas[f], ss); sd = fmaf(h[f], sad[f], sd); }

        uint4* rp = (uint4*)(rec1 + ((size_t)n << 3));   // 32B stride, aligned
        uint4 w0, w1;
        w0.x = __float_as_uint(ss);
        w0.y = __float_as_uint(sd);
        w0.z = pack2h(h[0], h[1]);
        w0.w = pack2h(h[2], h[3]);
        w1.x = pack2h(h[4], h[5]);
        w1.y = pack2h(h[6], h[7]);
        w1.z = 0u; w1.w = 0u;
        rp[0] = w0;
        rp[1] = w1;
    }

    // fused coarse-bucket histogram over dst (grid-stride, all threads)
    const int4* dv = (const int4*)dst;
    int total4 = N_EDGES / 4;
    for (int i = blockIdx.x * 256 + tid; i < total4; i += gridDim.x * 256) {
        int4 d = dv[i];
        atomicAdd(&lh[d.x >> 8], 1);
        atomicAdd(&lh[d.y >> 8], 1);
        atomicAdd(&lh[d.z >> 8], 1);
        atomicAdd(&lh[d.w >> 8], 1);
    }
    __syncthreads();
    for (int i = tid; i < NBC; i += 256) if (lh[i]) atomicAdd(&ccnt[i], lh[i]);
}

// ---------------- K2b: scan coarse counts; init padded cursors -------------
__global__ __launch_bounds__(512) void k2b_cscan(const int* __restrict__ ccnt,
                                                 int* __restrict__ cbase, int* __restrict__ cursC)
{
    __shared__ int s[512];
    int tid = threadIdx.x;
    int v = (tid < NBC) ? ccnt[tid] : 0;
    s[tid] = v;
    __syncthreads();
    for (int off = 1; off < 512; off <<= 1) {
        int t = (tid >= off) ? s[tid - off] : 0;
        __syncthreads();
        s[tid] += t;
        __syncthreads();
    }
    int ex = s[tid] - v;
    if (tid < NBC) { cbase[tid] = ex; cursC[tid * 16] = ex; }
    if (tid == NBC) cbase[NBC] = ex;   // == N_EDGES
}

// ------- KA: staged scatter — regs -> LDS bucket-sort -> parallel flush ----
__global__ __launch_bounds__(1024) void kA_stage(
    const int* __restrict__ src, const int* __restrict__ dst,
    int* __restrict__ cursC, unsigned int* __restrict__ bdata)
{
    __shared__ unsigned int stg[CHUNK];          // 16 KB
    __shared__ unsigned short aux[CHUNK];        //  8 KB (bucket id per slot)
    __shared__ int lh[NBC];
    __shared__ int lstart[NBC];
    __shared__ int lcur[NBC];
    __shared__ int tbase[NBC];
    int tid = threadIdx.x;

    for (int i = tid; i < NBC; i += 1024) lh[i] = 0;
    __syncthreads();

    int e0 = blockIdx.x * CHUNK;
    int ne = N_EDGES - e0; if (ne > CHUNK) ne = CHUNK;   // always multiple of 4
    int n4 = ne >> 2;                                    // 1024 (or 512 tail)
    const int4* dv = (const int4*)(dst + e0);
    const int4* sv = (const int4*)(src + e0);

    // pass 1: load chunk into registers + histogram (1 int4 per thread)
    int4 d0, s0;
    bool v0 = (tid < n4);
    if (v0) {
        d0 = dv[tid]; s0 = sv[tid];
        atomicAdd(&lh[d0.x >> 8], 1);
        atomicAdd(&lh[d0.y >> 8], 1);
        atomicAdd(&lh[d0.z >> 8], 1);
        atomicAdd(&lh[d0.w >> 8], 1);
    }
    __syncthreads();

    // wave-0 exclusive scan of 391 counts (7 per lane)
    if (tid < 64) {
        int base = tid * 7;
        int cnt[7];
        int s = 0;
#pragma unroll
        for (int k = 0; k < 7; ++k) {
            int b = base + k;
            cnt[k] = (b < NBC) ? lh[b] : 0;
            s += cnt[k];
        }
        int inc = s;
#pragma unroll
        for (int off = 1; off < 64; off <<= 1) {
            int t2 = __shfl_up(inc, off);
            if (tid >= off) inc += t2;
        }
        int ex = inc - s;
#pragma unroll
        for (int k = 0; k < 7; ++k) {
            int b = base + k;
            if (b < NBC) { lstart[b] = ex; lcur[b] = ex; ex += cnt[k]; }
        }
    }
    __syncthreads();

    // reserve global tickets — 391 independent padded-line atomics
    for (int b = tid; b < NBC; b += 1024) {
        int c = lh[b];
        tbase[b] = c ? atomicAdd(&cursC[b * 16], c) : 0;
    }

    // pass 2: scatter registers into LDS bucket order (+ record bucket id)
    if (v0) {
        int b, p;
        b = d0.x >> 8; p = atomicAdd(&lcur[b], 1); stg[p] = (unsigned)s0.x | ((unsigned)(d0.x & 255) << 17); aux[p] = (unsigned short)b;
        b = d0.y >> 8; p = atomicAdd(&lcur[b], 1); stg[p] = (unsigned)s0.y | ((unsigned)(d0.y & 255) << 17); aux[p] = (unsigned short)b;
        b = d0.z >> 8; p = atomicAdd(&lcur[b], 1); stg[p] = (unsigned)s0.z | ((unsigned)(d0.z & 255) << 17); aux[p] = (unsigned short)b;
        b = d0.w >> 8; p = atomicAdd(&lcur[b], 1); stg[p] = (unsigned)s0.w | ((unsigned)(d0.w & 255) << 17); aux[p] = (unsigned short)b;
    }
    __syncthreads();

    // flush: every lane active; consecutive i within a run -> consecutive bdata
    for (int i = tid; i < ne; i += 1024) {
        int bb = aux[i];
        bdata[tbase[bb] + (i - lstart[bb])] = stg[i];
    }
}

// ------- KF: fused node-sort + layer-1 aggregation (one block per bucket) --
__global__ __launch_bounds__(1024) void kF_sort_agg1(
    const int* __restrict__ cbase, unsigned int* __restrict__ bdata,
    const unsigned* __restrict__ rec1,
    const float* __restrict__ b1, const float* __restrict__ W2,
    const float* __restrict__ a2s, const float* __restrict__ a2d,
    float4* __restrict__ rec2, int* __restrict__ nptr)
{
    __shared__ unsigned int raw[CAPC];    // 72 KB
    __shared__ int cnt[COARSE];
    __shared__ int sstart[COARSE + 1];
    __shared__ int cur[COARSE];
    int tid = threadIdx.x;
    int c = blockIdx.x;
    int cb0 = cbase[c], cb1 = cbase[c + 1];
    int ne = cb1 - cb0;

    if (tid < COARSE) cnt[tid] = 0;
    __syncthreads();

    // load bucket + per-node count
    for (int i = tid; i < ne; i += 1024) {
        unsigned pk = bdata[cb0 + i];
        raw[i] = pk;
        atomicAdd(&cnt[pk >> 17], 1);
    }
    __syncthreads();

    // wave-0 exclusive scan of 256 counts (4 per lane)
    if (tid < 64) {
        int base = tid * 4;
        int c0 = cnt[base], c1 = cnt[base + 1], c2 = cnt[base + 2], c3 = cnt[base + 3];
        int s = c0 + c1 + c2 + c3;
        int inc = s;
#pragma unroll
        for (int off = 1; off < 64; off <<= 1) {
            int t2 = __shfl_up(inc, off);
            if (tid >= off) inc += t2;
        }
        int ex = inc - s;
        sstart[base]     = ex; cur[base]     = ex; ex += c0;
        sstart[base + 1] = ex; cur[base + 1] = ex; ex += c1;
        sstart[base + 2] = ex; cur[base + 2] = ex; ex += c2;
        sstart[base + 3] = ex; cur[base + 3] = ex;
        if (tid == 63) sstart[COARSE] = ex + c3;   // == ne
    }
    __syncthreads();

    if (tid < COARSE) {
        int nid = c * COARSE + tid;
        if (nid < N_NODES) nptr[nid] = cb0 + sstart[tid];
    }
    if (c == 0 && tid == 0) nptr[N_NODES] = N_EDGES;

    // counting-sort scatter: LDS raw -> global bdata (node-sorted, src only)
    for (int i = tid; i < ne; i += 1024) {
        unsigned pk = raw[i];
        int p = atomicAdd(&cur[pk >> 17], 1);
        bdata[cb0 + p] = pk & 0x1FFFF;
    }
    __syncthreads();   // drains vmcnt -> sorted bdata visible to all waves

    // aggregation: 4 threads per node, unroll-4 gathers from L2-hot bdata/rec1
    int nl = tid >> 2, q = tid & 3;
    int node = c * COARSE + nl;
    if (node >= N_NODES) return;
    int s0 = cb0 + sstart[nl], s1e = cb0 + sstart[nl + 1];
    float sdvn = __uint_as_float(rec1[((size_t)node << 3) + 1]);

    float z = 0.f;
    float acc[HID];
#pragma unroll
    for (int f = 0; f < HID; ++f) acc[f] = 0.f;

    int j = s0 + q;
    for (; j + 12 < s1e; j += 16) {
        int sA = bdata[j], sB = bdata[j + 4], sC = bdata[j + 8], sD = bdata[j + 12];
        const uint4* rA = (const uint4*)(rec1 + ((size_t)sA << 3));
        const uint4* rB = (const uint4*)(rec1 + ((size_t)sB << 3));
        const uint4* rC = (const uint4*)(rec1 + ((size_t)sC << 3));
        const uint4* rD = (const uint4*)(rec1 + ((size_t)sD << 3));
        uint4 a0 = rA[0]; uint2 a1u = *(const uint2*)(rA + 1);
        uint4 b0 = rB[0]; uint2 b1u = *(const uint2*)(rB + 1);
        uint4 c0v = rC[0]; uint2 c1u = *(const uint2*)(rC + 1);
        uint4 d0v = rD[0]; uint2 d1u = *(const uint2*)(rD + 1);
        float eA = __uint_as_float(a0.x) + sdvn; eA = (eA > 0.f) ? eA : NEG_SLOPE * eA;
        float eB = __uint_as_float(b0.x) + sdvn; eB = (eB > 0.f) ? eB : NEG_SLOPE * eB;
        float eC = __uint_as_float(c0v.x) + sdvn; eC = (eC > 0.f) ? eC : NEG_SLOPE * eC;
        float eD = __uint_as_float(d0v.x) + sdvn; eD = (eD > 0.f) ? eD : NEG_SLOPE * eD;
        float pA = __expf(eA - SHIFT1);
        float pB = __expf(eB - SHIFT1);
        float pC = __expf(eC - SHIFT1);
        float pD = __expf(eD - SHIFT1);
        z += (pA + pB) + (pC + pD);
        float2 fa01 = unpack2h(a0.z),  fa23 = unpack2h(a0.w),  fa45 = unpack2h(a1u.x), fa67 = unpack2h(a1u.y);
        float2 fb01 = unpack2h(b0.z),  fb23 = unpack2h(b0.w),  fb45 = unpack2h(b1u.x), fb67 = unpack2h(b1u.y);
        float2 fc01 = unpack2h(c0v.z), fc23 = unpack2h(c0v.w), fc45 = unpack2h(c1u.x), fc67 = unpack2h(c1u.y);
        float2 fd01 = unpack2h(d0v.z), fd23 = unpack2h(d0v.w), fd45 = unpack2h(d1u.x), fd67 = unpack2h(d1u.y);
        acc[0] += pA * fa01.x + pB * fb01.x + pC * fc01.x + pD * fd01.x;
        acc[1] += pA * fa01.y + pB * fb01.y + pC * fc01.y + pD * fd01.y;
        acc[2] += pA * fa23.x + pB * fb23.x + pC * fc23.x + pD * fd23.x;
        acc[3] += pA * fa23.y + pB * fb23.y + pC * fc23.y + pD * fd23.y;
        acc[4] += pA * fa45.x + pB * fb45.x + pC * fc45.x + pD * fd45.x;
        acc[5] += pA * fa45.y + pB * fb45.y + pC * fc45.y + pD * fd45.y;
        acc[6] += pA * fa67.x + pB * fb67.x + pC * fc67.x + pD * fd67.x;
        acc[7] += pA * fa67.y + pB * fb67.y + pC * fc67.y + pD * fd67.y;
    }
    for (; j < s1e; j += 4) {
        int s = bdata[j];
        const uint4* rp = (const uint4*)(rec1 + ((size_t)s << 3));
        uint4 v0 = rp[0];
        uint2 v1 = *(const uint2*)(rp + 1);
        float e = __uint_as_float(v0.x) + sdvn;
        e = (e > 0.f) ? e : NEG_SLOPE * e;
        float p = __expf(e - SHIFT1);
        z += p;
        float2 f01 = unpack2h(v0.z), f23 = unpack2h(v0.w);
        float2 f45 = unpack2h(v1.x), f67 = unpack2h(v1.y);
        acc[0] += p * f01.x; acc[1] += p * f01.y;
        acc[2] += p * f23.x; acc[3] += p * f23.y;
        acc[4] += p * f45.x; acc[5] += p * f45.y;
        acc[6] += p * f67.x; acc[7] += p * f67.y;
    }

#pragma unroll
    for (int off = 1; off < 4; off <<= 1) {
        z += __shfl_xor(z, off);
#pragma unroll
        for (int f = 0; f < HID; ++f) acc[f] += __shfl_xor(acc[f], off);
    }

    if (q == 0) {
        float inv = 1.f / (z + 1e-16f);
        float c0 = 0.f, c1 = 0.f;
#pragma unroll
        for (int f = 0; f < HID; ++f) {
            float hr = fmaxf(acc[f] * inv + b1[f], 0.f);
            c0 = fmaf(hr, W2[f * NCLS + 0], c0);
            c1 = fmaf(hr, W2[f * NCLS + 1], c1);
        }
        float s2sv = c0 * a2s[0] + c1 * a2s[1];
        float s2dv = c0 * a2d[0] + c1 * a2d[1];
        rec2[node] = make_float4(s2sv, c0, c1, s2dv);
    }
}

// ---------------- KAgg2: layer-2 agg, unroll-4 float4 gathers --------------
__global__ __launch_bounds__(256) void kAgg2(
    const int* __restrict__ nptr, const unsigned int* __restrict__ bdata,
    const float4* __restrict__ rec2,
    const float* __restrict__ b2, float* __restrict__ out)
{
    int gi = blockIdx.x * 256 + threadIdx.x;
    int n = gi >> 4, q = gi & 15;
    if (n >= N_NODES) return;

    int e0 = nptr[n], e1 = nptr[n + 1];
    float sdvn = rec2[n].w;
    float z = 0.f, a0 = 0.f, a1 = 0.f;

    int j = e0 + q;
    for (; j + 48 < e1; j += 64) {
        int sA = bdata[j];
        int sB = bdata[j + 16];
        int sC = bdata[j + 32];
        int sD = bdata[j + 48];
        float4 rA = rec2[sA];
        float4 rB = rec2[sB];
        float4 rC = rec2[sC];
        float4 rD = rec2[sD];
        float eA = rA.x + sdvn; eA = (eA > 0.f) ? eA : NEG_SLOPE * eA;
        float eB = rB.x + sdvn; eB = (eB > 0.f) ? eB : NEG_SLOPE * eB;
        float eC = rC.x + sdvn; eC = (eC > 0.f) ? eC : NEG_SLOPE * eC;
        float eD = rD.x + sdvn; eD = (eD > 0.f) ? eD : NEG_SLOPE * eD;
        float pA = __expf(eA - SHIFT2);
        float pB = __expf(eB - SHIFT2);
        float pC = __expf(eC - SHIFT2);
        float pD = __expf(eD - SHIFT2);
        z += (pA + pB) + (pC + pD);
        a0 += pA * rA.y + pB * rB.y + pC * rC.y + pD * rD.y;
        a1 += pA * rA.z + pB * rB.z + pC * rC.z + pD * rD.z;
    }
    for (; j < e1; j += 16) {
        int s = bdata[j];
        float4 r = rec2[s];
        float e = r.x + sdvn;
        e = (e > 0.f) ? e : NEG_SLOPE * e;
        float p = __expf(e - SHIFT2);
        z += p; a0 += p * r.y; a1 += p * r.z;
    }

#pragma unroll
    for (int off = 1; off < 16; off <<= 1) {
        z  += __shfl_xor(z, off);
        a0 += __shfl_xor(a0, off);
        a1 += __shfl_xor(a1, off);
    }

    if (q == 0) {
        float inv = 1.f / (z + 1e-16f);
        float o0 = a0 * inv + b2[0];
        float o1 = a1 * inv + b2[1];
        float mx = fmaxf(o0, o1);
        float lse = mx + __logf(__expf(o0 - mx) + __expf(o1 - mx));
        ((float2*)out)[n] = make_float2(o0 - lse, o1 - lse);
    }
}

// ---------------- host launch ----------------------------------------------
extern "C" void kernel_launch(void* const* d_in, const int* in_sizes, int n_in,
                              void* d_out, int out_size, void* d_ws, size_t ws_size,
                              hipStream_t stream) {
    const float* x   = (const float*)d_in[0];
    const float* W1  = (const float*)d_in[1];
    const float* a1s = (const float*)d_in[2];
    const float* a1d = (const float*)d_in[3];
    const float* b1  = (const float*)d_in[4];
    const float* W2  = (const float*)d_in[5];
    const float* a2s = (const float*)d_in[6];
    const float* a2d = (const float*)d_in[7];
    const float* b2  = (const float*)d_in[8];
    const int*   ei  = (const int*)d_in[9];
    const int* src = ei;
    const int* dst = ei + N_EDGES;

    char* ws = (char*)d_ws;
    unsigned* rec1  = (unsigned*)(ws + 0);         // 3,200,000 (100000 x 32B)
    float4*   rec2  = (float4*)  (ws + 4000000);   // 1,600,000 (100000 x 16B)
    int*      nptr  = (int*)     (ws + 5600000);   //   400,016
    int*      ccnt  = (int*)     (ws + 6000064);   //     1,564 -> pad
    int*      cbase = (int*)     (ws + 6001664);   //     1,568 -> pad
    int*      cursC = (int*)     (ws + 6003264);   //    25,024 (391 x 16 ints, 64B stride)
    unsigned int* bdata = (unsigned int*)(ws + 6028288);  // 25,600,000

    float* out = (float*)d_out;

    hipMemsetAsync(ccnt, 0, NBC * sizeof(int), stream);

    k0_node<<<(N_NODES + 255) / 256, 256, 0, stream>>>(x, W1, a1s, a1d, dst, rec1, ccnt);
    k2b_cscan<<<1, 512, 0, stream>>>(ccnt, cbase, cursC);
    kA_stage<<<NSTG, 1024, 0, stream>>>(src, dst, cursC, bdata);
    kF_sort_agg1<<<NBC, 1024, 0, stream>>>(cbase, bdata, rec1, b1, W2, a2s, a2d, rec2, nptr);
    kAgg2<<<(N_NODES * 16 + 255) / 256, 256, 0, stream>>>(nptr, bdata, rec2, b2, out);
}

// Round 15
// 187.918 us; speedup vs baseline: 1.1119x; 1.1119x over previous
//
#include <hip/hip_runtime.h>
#include <hip/hip_fp16.h>
#include <math.h>

#define N_NODES 100000
#define N_EDGES 6400000
#define F_IN 36
#define HID 8
#define NCLS 2
#define NEG_SLOPE 0.2f

#define COARSE 256                        // nodes per coarse bucket (dst >> 8)
#define NBC 391                           // ceil(N_NODES/256)
#define CAPC 18432                        // max edges per coarse bucket (mean ~16368, +16 sigma)
#define CHUNK 4096                        // edges staged per kA block
#define NSTG ((N_EDGES + CHUNK - 1) / CHUNK)   // 1563
#define SHIFT1 8.0f                       // softmax shift (softmax is shift-invariant)
#define SHIFT2 16.0f

// rec1: 32B-aligned record per node: [0]=s1s f32, [1]=s1d f32, [2..5]=h0..h7 fp16 pairs, [6..7]=pad

static __device__ __forceinline__ unsigned pack2h(float a, float b) {
    __half2 h = __float22half2_rn(make_float2(a, b));
    return *reinterpret_cast<unsigned*>(&h);
}
static __device__ __forceinline__ float2 unpack2h(unsigned u) {
    __half2 h = *reinterpret_cast<__half2*>(&u);
    return __half22float2(h);
}

// ------- K0: per-node rec1 (packed)  +  fused dst histogram ----------------
__global__ __launch_bounds__(256) void k0_node(
    const float* __restrict__ x, const float* __restrict__ W1,
    const float* __restrict__ a1s_g, const float* __restrict__ a1d_g,
    const int* __restrict__ dst,
    unsigned* __restrict__ rec1, int* __restrict__ ccnt)
{
    __shared__ float sW[F_IN * HID];
    __shared__ float sas[HID], sad[HID];
    __shared__ int lh[NBC];
    int tid = threadIdx.x;
    for (int i = tid; i < F_IN * HID; i += 256) sW[i] = W1[i];
    for (int i = tid; i < NBC; i += 256) lh[i] = 0;
    if (tid < HID) { sas[tid] = a1s_g[tid]; sad[tid] = a1d_g[tid]; }
    __syncthreads();

    int n = blockIdx.x * 256 + tid;
    if (n < N_NODES) {
        const float4* xp = (const float4*)(x + (size_t)n * F_IN);
        float h[HID];
#pragma unroll
        for (int f = 0; f < HID; ++f) h[f] = 0.f;
#pragma unroll
        for (int q = 0; q < F_IN / 4; ++q) {
            float4 v = xp[q];
            float vs[4] = {v.x, v.y, v.z, v.w};
#pragma unroll
            for (int j = 0; j < 4; ++j) {
                int k = q * 4 + j;
#pragma unroll
                for (int f = 0; f < HID; ++f) h[f] = fmaf(vs[j], sW[k * HID + f], h[f]);
            }
        }
        float ss = 0.f, sd = 0.f;
#pragma unroll
        for (int f = 0; f < HID; ++f) { ss = fmaf(h[f], sas[f], ss); sd = fmaf(h[f], sad[f], sd); }

        uint4* rp = (uint4*)(rec1 + ((size_t)n << 3));   // 32B stride, aligned
        uint4 w0, w1;
        w0.x = __float_as_uint(ss);
        w0.y = __float_as_uint(sd);
        w0.z = pack2h(h[0], h[1]);
        w0.w = pack2h(h[2], h[3]);
        w1.x = pack2h(h[4], h[5]);
        w1.y = pack2h(h[6], h[7]);
        w1.z = 0u; w1.w = 0u;
        rp[0] = w0;
        rp[1] = w1;
    }

    // fused coarse-bucket histogram over dst (grid-stride, all threads)
    const int4* dv = (const int4*)dst;
    int total4 = N_EDGES / 4;
    for (int i = blockIdx.x * 256 + tid; i < total4; i += gridDim.x * 256) {
        int4 d = dv[i];
        atomicAdd(&lh[d.x >> 8], 1);
        atomicAdd(&lh[d.y >> 8], 1);
        atomicAdd(&lh[d.z >> 8], 1);
        atomicAdd(&lh[d.w >> 8], 1);
    }
    __syncthreads();
    for (int i = tid; i < NBC; i += 256) if (lh[i]) atomicAdd(&ccnt[i], lh[i]);
}

// ---------------- K2b: scan coarse counts; init padded cursors -------------
__global__ __launch_bounds__(512) void k2b_cscan(const int* __restrict__ ccnt,
                                                 int* __restrict__ cbase, int* __restrict__ cursC)
{
    __shared__ int s[512];
    int tid = threadIdx.x;
    int v = (tid < NBC) ? ccnt[tid] : 0;
    s[tid] = v;
    __syncthreads();
    for (int off = 1; off < 512; off <<= 1) {
        int t = (tid >= off) ? s[tid - off] : 0;
        __syncthreads();
        s[tid] += t;
        __syncthreads();
    }
    int ex = s[tid] - v;
    if (tid < NBC) { cbase[tid] = ex; cursC[tid * 16] = ex; }
    if (tid == NBC) cbase[NBC] = ex;   // == N_EDGES
}

// ------- KA: staged scatter — regs -> LDS bucket-sort -> parallel flush ----
__global__ __launch_bounds__(1024) void kA_stage(
    const int* __restrict__ src, const int* __restrict__ dst,
    int* __restrict__ cursC, unsigned int* __restrict__ bdata)
{
    __shared__ unsigned int stg[CHUNK];          // 16 KB
    __shared__ unsigned short aux[CHUNK];        //  8 KB (bucket id per slot)
    __shared__ int lh[NBC];
    __shared__ int lstart[NBC];
    __shared__ int lcur[NBC];
    __shared__ int tbase[NBC];
    int tid = threadIdx.x;

    for (int i = tid; i < NBC; i += 1024) lh[i] = 0;
    __syncthreads();

    int e0 = blockIdx.x * CHUNK;
    int ne = N_EDGES - e0; if (ne > CHUNK) ne = CHUNK;   // always multiple of 4
    int n4 = ne >> 2;                                    // 1024 (or 512 tail)
    const int4* dv = (const int4*)(dst + e0);
    const int4* sv = (const int4*)(src + e0);

    // pass 1: load chunk into registers + histogram (1 int4 per thread)
    int4 d0, s0;
    bool v0 = (tid < n4);
    if (v0) {
        d0 = dv[tid]; s0 = sv[tid];
        atomicAdd(&lh[d0.x >> 8], 1);
        atomicAdd(&lh[d0.y >> 8], 1);
        atomicAdd(&lh[d0.z >> 8], 1);
        atomicAdd(&lh[d0.w >> 8], 1);
    }
    __syncthreads();

    // wave-0 exclusive scan of 391 counts (7 per lane)
    if (tid < 64) {
        int base = tid * 7;
        int cnt[7];
        int s = 0;
#pragma unroll
        for (int k = 0; k < 7; ++k) {
            int b = base + k;
            cnt[k] = (b < NBC) ? lh[b] : 0;
            s += cnt[k];
        }
        int inc = s;
#pragma unroll
        for (int off = 1; off < 64; off <<= 1) {
            int t2 = __shfl_up(inc, off);
            if (tid >= off) inc += t2;
        }
        int ex = inc - s;
#pragma unroll
        for (int k = 0; k < 7; ++k) {
            int b = base + k;
            if (b < NBC) { lstart[b] = ex; lcur[b] = ex; ex += cnt[k]; }
        }
    }
    __syncthreads();

    // reserve global tickets — 391 independent padded-line atomics
    for (int b = tid; b < NBC; b += 1024) {
        int c = lh[b];
        tbase[b] = c ? atomicAdd(&cursC[b * 16], c) : 0;
    }

    // pass 2: scatter registers into LDS bucket order (+ record bucket id)
    if (v0) {
        int b, p;
        b = d0.x >> 8; p = atomicAdd(&lcur[b], 1); stg[p] = (unsigned)s0.x | ((unsigned)(d0.x & 255) << 17); aux[p] = (unsigned short)b;
        b = d0.y >> 8; p = atomicAdd(&lcur[b], 1); stg[p] = (unsigned)s0.y | ((unsigned)(d0.y & 255) << 17); aux[p] = (unsigned short)b;
        b = d0.z >> 8; p = atomicAdd(&lcur[b], 1); stg[p] = (unsigned)s0.z | ((unsigned)(d0.z & 255) << 17); aux[p] = (unsigned short)b;
        b = d0.w >> 8; p = atomicAdd(&lcur[b], 1); stg[p] = (unsigned)s0.w | ((unsigned)(d0.w & 255) << 17); aux[p] = (unsigned short)b;
    }
    __syncthreads();

    // flush: every lane active; consecutive i within a run -> consecutive bdata
    for (int i = tid; i < ne; i += 1024) {
        int bb = aux[i];
        bdata[tbase[bb] + (i - lstart[bb])] = stg[i];
    }
}

// ------- KB: in-LDS node-granularity sort; emits nptr CSR (512T) -----------
__global__ __launch_bounds__(512) void kB_sort(
    const int* __restrict__ cbase, unsigned int* __restrict__ bdata,
    int* __restrict__ nptr)
{
    __shared__ unsigned int raw[CAPC];    // 72 KB
    __shared__ int cnt[COARSE];
    __shared__ int sstart[COARSE];
    __shared__ int cur[COARSE];
    int tid = threadIdx.x;
    int c = blockIdx.x;
    int cb0 = cbase[c], cb1 = cbase[c + 1];
    int ne = cb1 - cb0;

    if (tid < COARSE) cnt[tid] = 0;
    __syncthreads();

    for (int i = tid; i < ne; i += 512) {
        unsigned pk = bdata[cb0 + i];
        raw[i] = pk;
        atomicAdd(&cnt[pk >> 17], 1);     // no return needed -> independent
    }
    __syncthreads();

    // wave-0 exclusive scan of 256 counts (4 per lane)
    if (tid < 64) {
        int base = tid * 4;
        int c0 = cnt[base], c1 = cnt[base + 1], c2 = cnt[base + 2], c3 = cnt[base + 3];
        int s = c0 + c1 + c2 + c3;
        int inc = s;
#pragma unroll
        for (int off = 1; off < 64; off <<= 1) {
            int t2 = __shfl_up(inc, off);
            if (tid >= off) inc += t2;
        }
        int ex = inc - s;
        sstart[base]     = ex; cur[base]     = ex; ex += c0;
        sstart[base + 1] = ex; cur[base + 1] = ex; ex += c1;
        sstart[base + 2] = ex; cur[base + 2] = ex; ex += c2;
        sstart[base + 3] = ex; cur[base + 3] = ex;
    }
    __syncthreads();

    if (tid < COARSE) {
        int nid = c * COARSE + tid;
        if (nid < N_NODES) nptr[nid] = cb0 + sstart[tid];
    }
    if (c == 0 && tid == 0) nptr[N_NODES] = N_EDGES;

    for (int i = tid; i < ne; i += 512) {
        unsigned pk = raw[i];
        int loc = pk >> 17;
        int p = atomicAdd(&cur[loc], 1);
        bdata[cb0 + p] = pk & 0x1FFFF;    // node-sorted: store src only
    }
}

// ---------------- KAgg1: layer-1 agg, unroll-4 packed gathers --------------
__global__ __launch_bounds__(256) void kAgg1(
    const int* __restrict__ nptr, const unsigned int* __restrict__ bdata,
    const unsigned* __restrict__ rec1,
    const float* __restrict__ b1, const float* __restrict__ W2,
    const float* __restrict__ a2s, const float* __restrict__ a2d,
    float4* __restrict__ rec2)
{
    int gi = blockIdx.x * 256 + threadIdx.x;
    int n = gi >> 4, q = gi & 15;
    if (n >= N_NODES) return;

    int e0 = nptr[n], e1 = nptr[n + 1];
    float sdvn = __uint_as_float(rec1[((size_t)n << 3) + 1]);
    float z = 0.f;
    float acc[HID];
#pragma unroll
    for (int f = 0; f < HID; ++f) acc[f] = 0.f;

    int j = e0 + q;
    for (; j + 48 < e1; j += 64) {
        int sA = bdata[j], sB = bdata[j + 16], sC = bdata[j + 32], sD = bdata[j + 48];
        const uint4* rA = (const uint4*)(rec1 + ((size_t)sA << 3));
        const uint4* rB = (const uint4*)(rec1 + ((size_t)sB << 3));
        const uint4* rC = (const uint4*)(rec1 + ((size_t)sC << 3));
        const uint4* rD = (const uint4*)(rec1 + ((size_t)sD << 3));
        uint4 a0 = rA[0];  uint2 a1u = *(const uint2*)(rA + 1);
        uint4 b0 = rB[0];  uint2 b1u = *(const uint2*)(rB + 1);
        uint4 c0v = rC[0]; uint2 c1u = *(const uint2*)(rC + 1);
        uint4 d0v = rD[0]; uint2 d1u = *(const uint2*)(rD + 1);
        float eA = __uint_as_float(a0.x) + sdvn;  eA = (eA > 0.f) ? eA : NEG_SLOPE * eA;
        float eB = __uint_as_float(b0.x) + sdvn;  eB = (eB > 0.f) ? eB : NEG_SLOPE * eB;
        float eC = __uint_as_float(c0v.x) + sdvn; eC = (eC > 0.f) ? eC : NEG_SLOPE * eC;
        float eD = __uint_as_float(d0v.x) + sdvn; eD = (eD > 0.f) ? eD : NEG_SLOPE * eD;
        float pA = __expf(eA - SHIFT1);
        float pB = __expf(eB - SHIFT1);
        float pC = __expf(eC - SHIFT1);
        float pD = __expf(eD - SHIFT1);
        z += (pA + pB) + (pC + pD);
        float2 fa01 = unpack2h(a0.z),  fa23 = unpack2h(a0.w),  fa45 = unpack2h(a1u.x), fa67 = unpack2h(a1u.y);
        float2 fb01 = unpack2h(b0.z),  fb23 = unpack2h(b0.w),  fb45 = unpack2h(b1u.x), fb67 = unpack2h(b1u.y);
        float2 fc01 = unpack2h(c0v.z), fc23 = unpack2h(c0v.w), fc45 = unpack2h(c1u.x), fc67 = unpack2h(c1u.y);
        float2 fd01 = unpack2h(d0v.z), fd23 = unpack2h(d0v.w), fd45 = unpack2h(d1u.x), fd67 = unpack2h(d1u.y);
        acc[0] += pA * fa01.x + pB * fb01.x + pC * fc01.x + pD * fd01.x;
        acc[1] += pA * fa01.y + pB * fb01.y + pC * fc01.y + pD * fd01.y;
        acc[2] += pA * fa23.x + pB * fb23.x + pC * fc23.x + pD * fd23.x;
        acc[3] += pA * fa23.y + pB * fb23.y + pC * fc23.y + pD * fd23.y;
        acc[4] += pA * fa45.x + pB * fb45.x + pC * fc45.x + pD * fd45.x;
        acc[5] += pA * fa45.y + pB * fb45.y + pC * fc45.y + pD * fd45.y;
        acc[6] += pA * fa67.x + pB * fb67.x + pC * fc67.x + pD * fd67.x;
        acc[7] += pA * fa67.y + pB * fb67.y + pC * fc67.y + pD * fd67.y;
    }
    for (; j < e1; j += 16) {
        int s = bdata[j];
        const uint4* rp = (const uint4*)(rec1 + ((size_t)s << 3));
        uint4 v0 = rp[0];
        uint2 v1 = *(const uint2*)(rp + 1);
        float e = __uint_as_float(v0.x) + sdvn;
        e = (e > 0.f) ? e : NEG_SLOPE * e;
        float p = __expf(e - SHIFT1);
        z += p;
        float2 f01 = unpack2h(v0.z), f23 = unpack2h(v0.w);
        float2 f45 = unpack2h(v1.x), f67 = unpack2h(v1.y);
        acc[0] += p * f01.x; acc[1] += p * f01.y;
        acc[2] += p * f23.x; acc[3] += p * f23.y;
        acc[4] += p * f45.x; acc[5] += p * f45.y;
        acc[6] += p * f67.x; acc[7] += p * f67.y;
    }

#pragma unroll
    for (int off = 1; off < 16; off <<= 1) {
        z += __shfl_xor(z, off);
#pragma unroll
        for (int f = 0; f < HID; ++f) acc[f] += __shfl_xor(acc[f], off);
    }

    if (q == 0) {
        float inv = 1.f / (z + 1e-16f);
        float c0 = 0.f, c1 = 0.f;
#pragma unroll
        for (int f = 0; f < HID; ++f) {
            float hr = fmaxf(acc[f] * inv + b1[f], 0.f);
            c0 = fmaf(hr, W2[f * NCLS + 0], c0);
            c1 = fmaf(hr, W2[f * NCLS + 1], c1);
        }
        float s2sv = c0 * a2s[0] + c1 * a2s[1];
        float s2dv = c0 * a2d[0] + c1 * a2d[1];
        rec2[n] = make_float4(s2sv, c0, c1, s2dv);
    }
}

// ---------------- KAgg2: layer-2 agg, unroll-4 float4 gathers --------------
__global__ __launch_bounds__(256) void kAgg2(
    const int* __restrict__ nptr, const unsigned int* __restrict__ bdata,
    const float4* __restrict__ rec2,
    const float* __restrict__ b2, float* __restrict__ out)
{
    int gi = blockIdx.x * 256 + threadIdx.x;
    int n = gi >> 4, q = gi & 15;
    if (n >= N_NODES) return;

    int e0 = nptr[n], e1 = nptr[n + 1];
    float sdvn = rec2[n].w;
    float z = 0.f, a0 = 0.f, a1 = 0.f;

    int j = e0 + q;
    for (; j + 48 < e1; j += 64) {
        int sA = bdata[j];
        int sB = bdata[j + 16];
        int sC = bdata[j + 32];
        int sD = bdata[j + 48];
        float4 rA = rec2[sA];
        float4 rB = rec2[sB];
        float4 rC = rec2[sC];
        float4 rD = rec2[sD];
        float eA = rA.x + sdvn; eA = (eA > 0.f) ? eA : NEG_SLOPE * eA;
        float eB = rB.x + sdvn; eB = (eB > 0.f) ? eB : NEG_SLOPE * eB;
        float eC = rC.x + sdvn; eC = (eC > 0.f) ? eC : NEG_SLOPE * eC;
        float eD = rD.x + sdvn; eD = (eD > 0.f) ? eD : NEG_SLOPE * eD;
        float pA = __expf(eA - SHIFT2);
        float pB = __expf(eB - SHIFT2);
        float pC = __expf(eC - SHIFT2);
        float pD = __expf(eD - SHIFT2);
        z += (pA + pB) + (pC + pD);
        a0 += pA * rA.y + pB * rB.y + pC * rC.y + pD * rD.y;
        a1 += pA * rA.z + pB * rB.z + pC * rC.z + pD * rD.z;
    }
    for (; j < e1; j += 16) {
        int s = bdata[j];
        float4 r = rec2[s];
        float e = r.x + sdvn;
        e = (e > 0.f) ? e : NEG_SLOPE * e;
        float p = __expf(e - SHIFT2);
        z += p; a0 += p * r.y; a1 += p * r.z;
    }

#pragma unroll
    for (int off = 1; off < 16; off <<= 1) {
        z  += __shfl_xor(z, off);
        a0 += __shfl_xor(a0, off);
        a1 += __shfl_xor(a1, off);
    }

    if (q == 0) {
        float inv = 1.f / (z + 1e-16f);
        float o0 = a0 * inv + b2[0];
        float o1 = a1 * inv + b2[1];
        float mx = fmaxf(o0, o1);
        float lse = mx + __logf(__expf(o0 - mx) + __expf(o1 - mx));
        ((float2*)out)[n] = make_float2(o0 - lse, o1 - lse);
    }
}

// ---------------- host launch ----------------------------------------------
extern "C" void kernel_launch(void* const* d_in, const int* in_sizes, int n_in,
                              void* d_out, int out_size, void* d_ws, size_t ws_size,
                              hipStream_t stream) {
    const float* x   = (const float*)d_in[0];
    const float* W1  = (const float*)d_in[1];
    const float* a1s = (const float*)d_in[2];
    const float* a1d = (const float*)d_in[3];
    const float* b1  = (const float*)d_in[4];
    const float* W2  = (const float*)d_in[5];
    const float* a2s = (const float*)d_in[6];
    const float* a2d = (const float*)d_in[7];
    const float* b2  = (const float*)d_in[8];
    const int*   ei  = (const int*)d_in[9];
    const int* src = ei;
    const int* dst = ei + N_EDGES;

    char* ws = (char*)d_ws;
    unsigned* rec1  = (unsigned*)(ws + 0);         // 3,200,000 (100000 x 32B)
    float4*   rec2  = (float4*)  (ws + 4000000);   // 1,600,000 (100000 x 16B)
    int*      nptr  = (int*)     (ws + 5600000);   //   400,016
    int*      ccnt  = (int*)     (ws + 6000064);   //     1,564 -> pad
    int*      cbase = (int*)     (ws + 6001664);   //     1,568 -> pad
    int*      cursC = (int*)     (ws + 6003264);   //    25,024 (391 x 16 ints, 64B stride)
    unsigned int* bdata = (unsigned int*)(ws + 6028288);  // 25,600,000

    float* out = (float*)d_out;

    hipMemsetAsync(ccnt, 0, NBC * sizeof(int), stream);

    k0_node<<<(N_NODES + 255) / 256, 256, 0, stream>>>(x, W1, a1s, a1d, dst, rec1, ccnt);
    k2b_cscan<<<1, 512, 0, stream>>>(ccnt, cbase, cursC);
    kA_stage<<<NSTG, 1024, 0, stream>>>(src, dst, cursC, bdata);
    kB_sort<<<NBC, 512, 0, stream>>>(cbase, bdata, nptr);
    kAgg1<<<(N_NODES * 16 + 255) / 256, 256, 0, stream>>>(nptr, bdata, rec1,
                                                          b1, W2, a2s, a2d, rec2);
    kAgg2<<<(N_NODES * 16 + 255) / 256, 256, 0, stream>>>(nptr, bdata, rec2, b2, out);
}

// Round 16
// 177.416 us; speedup vs baseline: 1.1777x; 1.0592x over previous
//
#include <hip/hip_runtime.h>
#include <hip/hip_fp16.h>
#include <math.h>

#define N_NODES 100000
#define N_EDGES 6400000
#define F_IN 36
#define HID 8
#define NCLS 2
#define NEG_SLOPE 0.2f

#define COARSE 256                        // nodes per coarse bucket (dst >> 8)
#define NBC 391                           // ceil(N_NODES/256)
#define CAPC 18432                        // max edges per coarse bucket (mean ~16368, +16 sigma)
#define CHUNK 4096                        // edges staged per kA block
#define NSTG ((N_EDGES + CHUNK - 1) / CHUNK)   // 1563
#define SHIFT1 8.0f                       // softmax shift (softmax is shift-invariant)
#define SHIFT2 16.0f

// rec1: 16B record per node = h0..h7 fp16 (ONE uint4 gather per edge)
// s1d:  separate f32 array, read once per destination node
// rec2: 8B record per node = {c0,c1} f32 (ONE dwordx2 gather per edge);
//       s2s/s2d recomputed from a2s/a2d in registers

static __device__ __forceinline__ unsigned pack2h(float a, float b) {
    __half2 h = __float22half2_rn(make_float2(a, b));
    return *reinterpret_cast<unsigned*>(&h);
}
static __device__ __forceinline__ float2 unpack2h(unsigned u) {
    __half2 h = *reinterpret_cast<__half2*>(&u);
    return __half22float2(h);
}

// ------- K0: per-node rec1 (fp16 h) + s1d  +  fused dst histogram ----------
__global__ __launch_bounds__(256) void k0_node(
    const float* __restrict__ x, const float* __restrict__ W1,
    const float* __restrict__ a1d_g,
    const int* __restrict__ dst,
    uint4* __restrict__ rec1, float* __restrict__ s1d, int* __restrict__ ccnt)
{
    __shared__ float sW[F_IN * HID];
    __shared__ float sad[HID];
    __shared__ int lh[NBC];
    int tid = threadIdx.x;
    for (int i = tid; i < F_IN * HID; i += 256) sW[i] = W1[i];
    for (int i = tid; i < NBC; i += 256) lh[i] = 0;
    if (tid < HID) sad[tid] = a1d_g[tid];
    __syncthreads();

    int n = blockIdx.x * 256 + tid;
    if (n < N_NODES) {
        const float4* xp = (const float4*)(x + (size_t)n * F_IN);
        float h[HID];
#pragma unroll
        for (int f = 0; f < HID; ++f) h[f] = 0.f;
#pragma unroll
        for (int q = 0; q < F_IN / 4; ++q) {
            float4 v = xp[q];
            float vs[4] = {v.x, v.y, v.z, v.w};
#pragma unroll
            for (int j = 0; j < 4; ++j) {
                int k = q * 4 + j;
#pragma unroll
                for (int f = 0; f < HID; ++f) h[f] = fmaf(vs[j], sW[k * HID + f], h[f]);
            }
        }
        float sd = 0.f;
#pragma unroll
        for (int f = 0; f < HID; ++f) sd = fmaf(h[f], sad[f], sd);

        uint4 w;
        w.x = pack2h(h[0], h[1]);
        w.y = pack2h(h[2], h[3]);
        w.z = pack2h(h[4], h[5]);
        w.w = pack2h(h[6], h[7]);
        rec1[n] = w;
        s1d[n] = sd;
    }

    // fused coarse-bucket histogram over dst (grid-stride, all threads)
    const int4* dv = (const int4*)dst;
    int total4 = N_EDGES / 4;
    for (int i = blockIdx.x * 256 + tid; i < total4; i += gridDim.x * 256) {
        int4 d = dv[i];
        atomicAdd(&lh[d.x >> 8], 1);
        atomicAdd(&lh[d.y >> 8], 1);
        atomicAdd(&lh[d.z >> 8], 1);
        atomicAdd(&lh[d.w >> 8], 1);
    }
    __syncthreads();
    for (int i = tid; i < NBC; i += 256) if (lh[i]) atomicAdd(&ccnt[i], lh[i]);
}

// ---------------- K2b: scan coarse counts; init padded cursors -------------
__global__ __launch_bounds__(512) void k2b_cscan(const int* __restrict__ ccnt,
                                                 int* __restrict__ cbase, int* __restrict__ cursC)
{
    __shared__ int s[512];
    int tid = threadIdx.x;
    int v = (tid < NBC) ? ccnt[tid] : 0;
    s[tid] = v;
    __syncthreads();
    for (int off = 1; off < 512; off <<= 1) {
        int t = (tid >= off) ? s[tid - off] : 0;
        __syncthreads();
        s[tid] += t;
        __syncthreads();
    }
    int ex = s[tid] - v;
    if (tid < NBC) { cbase[tid] = ex; cursC[tid * 16] = ex; }
    if (tid == NBC) cbase[NBC] = ex;   // == N_EDGES
}

// ------- KA: staged scatter — regs -> LDS bucket-sort -> parallel flush ----
__global__ __launch_bounds__(1024) void kA_stage(
    const int* __restrict__ src, const int* __restrict__ dst,
    int* __restrict__ cursC, unsigned int* __restrict__ bdata)
{
    __shared__ unsigned int stg[CHUNK];          // 16 KB
    __shared__ unsigned short aux[CHUNK];        //  8 KB (bucket id per slot)
    __shared__ int lh[NBC];
    __shared__ int lstart[NBC];
    __shared__ int lcur[NBC];
    __shared__ int tbase[NBC];
    int tid = threadIdx.x;

    for (int i = tid; i < NBC; i += 1024) lh[i] = 0;
    __syncthreads();

    int e0 = blockIdx.x * CHUNK;
    int ne = N_EDGES - e0; if (ne > CHUNK) ne = CHUNK;   // always multiple of 4
    int n4 = ne >> 2;
    const int4* dv = (const int4*)(dst + e0);
    const int4* sv = (const int4*)(src + e0);

    // pass 1: load chunk into registers + histogram (1 int4 per thread)
    int4 d0, s0;
    bool v0 = (tid < n4);
    if (v0) {
        d0 = dv[tid]; s0 = sv[tid];
        atomicAdd(&lh[d0.x >> 8], 1);
        atomicAdd(&lh[d0.y >> 8], 1);
        atomicAdd(&lh[d0.z >> 8], 1);
        atomicAdd(&lh[d0.w >> 8], 1);
    }
    __syncthreads();

    // wave-0 exclusive scan of 391 counts (7 per lane)
    if (tid < 64) {
        int base = tid * 7;
        int cnt[7];
        int s = 0;
#pragma unroll
        for (int k = 0; k < 7; ++k) {
            int b = base + k;
            cnt[k] = (b < NBC) ? lh[b] : 0;
            s += cnt[k];
        }
        int inc = s;
#pragma unroll
        for (int off = 1; off < 64; off <<= 1) {
            int t2 = __shfl_up(inc, off);
            if (tid >= off) inc += t2;
        }
        int ex = inc - s;
#pragma unroll
        for (int k = 0; k < 7; ++k) {
            int b = base + k;
            if (b < NBC) { lstart[b] = ex; lcur[b] = ex; ex += cnt[k]; }
        }
    }
    __syncthreads();

    // reserve global tickets — 391 independent padded-line atomics
    for (int b = tid; b < NBC; b += 1024) {
        int c = lh[b];
        tbase[b] = c ? atomicAdd(&cursC[b * 16], c) : 0;
    }

    // pass 2: scatter registers into LDS bucket order (+ record bucket id)
    if (v0) {
        int b, p;
        b = d0.x >> 8; p = atomicAdd(&lcur[b], 1); stg[p] = (unsigned)s0.x | ((unsigned)(d0.x & 255) << 17); aux[p] = (unsigned short)b;
        b = d0.y >> 8; p = atomicAdd(&lcur[b], 1); stg[p] = (unsigned)s0.y | ((unsigned)(d0.y & 255) << 17); aux[p] = (unsigned short)b;
        b = d0.z >> 8; p = atomicAdd(&lcur[b], 1); stg[p] = (unsigned)s0.z | ((unsigned)(d0.z & 255) << 17); aux[p] = (unsigned short)b;
        b = d0.w >> 8; p = atomicAdd(&lcur[b], 1); stg[p] = (unsigned)s0.w | ((unsigned)(d0.w & 255) << 17); aux[p] = (unsigned short)b;
    }
    __syncthreads();

    // flush: every lane active; consecutive i within a run -> consecutive bdata
    for (int i = tid; i < ne; i += 1024) {
        int bb = aux[i];
        bdata[tbase[bb] + (i - lstart[bb])] = stg[i];
    }
}

// ------- KB: in-LDS node-granularity sort; emits nptr CSR (512T) -----------
__global__ __launch_bounds__(512) void kB_sort(
    const int* __restrict__ cbase, unsigned int* __restrict__ bdata,
    int* __restrict__ nptr)
{
    __shared__ unsigned int raw[CAPC];    // 72 KB
    __shared__ int cnt[COARSE];
    __shared__ int sstart[COARSE];
    __shared__ int cur[COARSE];
    int tid = threadIdx.x;
    int c = blockIdx.x;
    int cb0 = cbase[c], cb1 = cbase[c + 1];
    int ne = cb1 - cb0;

    if (tid < COARSE) cnt[tid] = 0;
    __syncthreads();

    for (int i = tid; i < ne; i += 512) {
        unsigned pk = bdata[cb0 + i];
        raw[i] = pk;
        atomicAdd(&cnt[pk >> 17], 1);     // no return needed -> independent
    }
    __syncthreads();

    // wave-0 exclusive scan of 256 counts (4 per lane)
    if (tid < 64) {
        int base = tid * 4;
        int c0 = cnt[base], c1 = cnt[base + 1], c2 = cnt[base + 2], c3 = cnt[base + 3];
        int s = c0 + c1 + c2 + c3;
        int inc = s;
#pragma unroll
        for (int off = 1; off < 64; off <<= 1) {
            int t2 = __shfl_up(inc, off);
            if (tid >= off) inc += t2;
        }
        int ex = inc - s;
        sstart[base]     = ex; cur[base]     = ex; ex += c0;
        sstart[base + 1] = ex; cur[base + 1] = ex; ex += c1;
        sstart[base + 2] = ex; cur[base + 2] = ex; ex += c2;
        sstart[base + 3] = ex; cur[base + 3] = ex;
    }
    __syncthreads();

    if (tid < COARSE) {
        int nid = c * COARSE + tid;
        if (nid < N_NODES) nptr[nid] = cb0 + sstart[tid];
    }
    if (c == 0 && tid == 0) nptr[N_NODES] = N_EDGES;

    for (int i = tid; i < ne; i += 512) {
        unsigned pk = raw[i];
        int loc = pk >> 17;
        int p = atomicAdd(&cur[loc], 1);
        bdata[cb0 + p] = pk & 0x1FFFF;    // node-sorted: store src only
    }
}

// ---------------- KAgg1: layer-1 agg, ONE uint4 gather per edge ------------
__global__ __launch_bounds__(256) void kAgg1(
    const int* __restrict__ nptr, const unsigned int* __restrict__ bdata,
    const uint4* __restrict__ rec1, const float* __restrict__ s1d,
    const float* __restrict__ a1s_g,
    const float* __restrict__ b1, const float* __restrict__ W2,
    const float* __restrict__ a2s, const float* __restrict__ a2d,
    float2* __restrict__ rec2)
{
    int gi = blockIdx.x * 256 + threadIdx.x;
    int n = gi >> 4, q = gi & 15;
    if (n >= N_NODES) return;

    float as0 = a1s_g[0], as1 = a1s_g[1], as2 = a1s_g[2], as3 = a1s_g[3];
    float as4 = a1s_g[4], as5 = a1s_g[5], as6 = a1s_g[6], as7 = a1s_g[7];

    int e0 = nptr[n], e1 = nptr[n + 1];
    float sdvn = s1d[n];
    float z = 0.f;
    float acc[HID];
#pragma unroll
    for (int f = 0; f < HID; ++f) acc[f] = 0.f;

    int j = e0 + q;
    for (; j + 48 < e1; j += 64) {
        int sA = bdata[j], sB = bdata[j + 16], sC = bdata[j + 32], sD = bdata[j + 48];
        uint4 ha = rec1[sA];
        uint4 hb = rec1[sB];
        uint4 hc = rec1[sC];
        uint4 hd = rec1[sD];
        float2 fa01 = unpack2h(ha.x), fa23 = unpack2h(ha.y), fa45 = unpack2h(ha.z), fa67 = unpack2h(ha.w);
        float2 fb01 = unpack2h(hb.x), fb23 = unpack2h(hb.y), fb45 = unpack2h(hb.z), fb67 = unpack2h(hb.w);
        float2 fc01 = unpack2h(hc.x), fc23 = unpack2h(hc.y), fc45 = unpack2h(hc.z), fc67 = unpack2h(hc.w);
        float2 fd01 = unpack2h(hd.x), fd23 = unpack2h(hd.y), fd45 = unpack2h(hd.z), fd67 = unpack2h(hd.w);
        float ssA = fa01.x*as0 + fa01.y*as1 + fa23.x*as2 + fa23.y*as3
                  + fa45.x*as4 + fa45.y*as5 + fa67.x*as6 + fa67.y*as7;
        float ssB = fb01.x*as0 + fb01.y*as1 + fb23.x*as2 + fb23.y*as3
                  + fb45.x*as4 + fb45.y*as5 + fb67.x*as6 + fb67.y*as7;
        float ssC = fc01.x*as0 + fc01.y*as1 + fc23.x*as2 + fc23.y*as3
                  + fc45.x*as4 + fc45.y*as5 + fc67.x*as6 + fc67.y*as7;
        float ssD = fd01.x*as0 + fd01.y*as1 + fd23.x*as2 + fd23.y*as3
                  + fd45.x*as4 + fd45.y*as5 + fd67.x*as6 + fd67.y*as7;
        float eA = ssA + sdvn; eA = (eA > 0.f) ? eA : NEG_SLOPE * eA;
        float eB = ssB + sdvn; eB = (eB > 0.f) ? eB : NEG_SLOPE * eB;
        float eC = ssC + sdvn; eC = (eC > 0.f) ? eC : NEG_SLOPE * eC;
        float eD = ssD + sdvn; eD = (eD > 0.f) ? eD : NEG_SLOPE * eD;
        float pA = __expf(eA - SHIFT1);
        float pB = __expf(eB - SHIFT1);
        float pC = __expf(eC - SHIFT1);
        float pD = __expf(eD - SHIFT1);
        z += (pA + pB) + (pC + pD);
        acc[0] += pA * fa01.x + pB * fb01.x + pC * fc01.x + pD * fd01.x;
        acc[1] += pA * fa01.y + pB * fb01.y + pC * fc01.y + pD * fd01.y;
        acc[2] += pA * fa23.x + pB * fb23.x + pC * fc23.x + pD * fd23.x;
        acc[3] += pA * fa23.y + pB * fb23.y + pC * fc23.y + pD * fd23.y;
        acc[4] += pA * fa45.x + pB * fb45.x + pC * fc45.x + pD * fd45.x;
        acc[5] += pA * fa45.y + pB * fb45.y + pC * fc45.y + pD * fd45.y;
        acc[6] += pA * fa67.x + pB * fb67.x + pC * fc67.x + pD * fd67.x;
        acc[7] += pA * fa67.y + pB * fb67.y + pC * fc67.y + pD * fd67.y;
    }
    for (; j < e1; j += 16) {
        int s = bdata[j];
        uint4 hv = rec1[s];
        float2 f01 = unpack2h(hv.x), f23 = unpack2h(hv.y);
        float2 f45 = unpack2h(hv.z), f67 = unpack2h(hv.w);
        float ss = f01.x*as0 + f01.y*as1 + f23.x*as2 + f23.y*as3
                 + f45.x*as4 + f45.y*as5 + f67.x*as6 + f67.y*as7;
        float e = ss + sdvn;
        e = (e > 0.f) ? e : NEG_SLOPE * e;
        float p = __expf(e - SHIFT1);
        z += p;
        acc[0] += p * f01.x; acc[1] += p * f01.y;
        acc[2] += p * f23.x; acc[3] += p * f23.y;
        acc[4] += p * f45.x; acc[5] += p * f45.y;
        acc[6] += p * f67.x; acc[7] += p * f67.y;
    }

#pragma unroll
    for (int off = 1; off < 16; off <<= 1) {
        z += __shfl_xor(z, off);
#pragma unroll
        for (int f = 0; f < HID; ++f) acc[f] += __shfl_xor(acc[f], off);
    }

    if (q == 0) {
        float inv = 1.f / (z + 1e-16f);
        float c0 = 0.f, c1 = 0.f;
#pragma unroll
        for (int f = 0; f < HID; ++f) {
            float hr = fmaxf(acc[f] * inv + b1[f], 0.f);
            c0 = fmaf(hr, W2[f * NCLS + 0], c0);
            c1 = fmaf(hr, W2[f * NCLS + 1], c1);
        }
        rec2[n] = make_float2(c0, c1);
    }
}

// ---------------- KAgg2: layer-2 agg, ONE float2 gather per edge -----------
__global__ __launch_bounds__(256) void kAgg2(
    const int* __restrict__ nptr, const unsigned int* __restrict__ bdata,
    const float2* __restrict__ rec2,
    const float* __restrict__ a2s, const float* __restrict__ a2d,
    const float* __restrict__ b2, float* __restrict__ out)
{
    int gi = blockIdx.x * 256 + threadIdx.x;
    int n = gi >> 4, q = gi & 15;
    if (n >= N_NODES) return;

    float ws0 = a2s[0], ws1 = a2s[1];
    float wd0 = a2d[0], wd1 = a2d[1];

    int e0 = nptr[n], e1 = nptr[n + 1];
    float2 rn = rec2[n];
    float sdvn = rn.x * wd0 + rn.y * wd1;
    float z = 0.f, a0 = 0.f, a1 = 0.f;

    int j = e0 + q;
    for (; j + 48 < e1; j += 64) {
        int sA = bdata[j];
        int sB = bdata[j + 16];
        int sC = bdata[j + 32];
        int sD = bdata[j + 48];
        float2 rA = rec2[sA];
        float2 rB = rec2[sB];
        float2 rC = rec2[sC];
        float2 rD = rec2[sD];
        float eA = rA.x * ws0 + rA.y * ws1 + sdvn; eA = (eA > 0.f) ? eA : NEG_SLOPE * eA;
        float eB = rB.x * ws0 + rB.y * ws1 + sdvn; eB = (eB > 0.f) ? eB : NEG_SLOPE * eB;
        float eC = rC.x * ws0 + rC.y * ws1 + sdvn; eC = (eC > 0.f) ? eC : NEG_SLOPE * eC;
        float eD = rD.x * ws0 + rD.y * ws1 + sdvn; eD = (eD > 0.f) ? eD : NEG_SLOPE * eD;
        float pA = __expf(eA - SHIFT2);
        float pB = __expf(eB - SHIFT2);
        float pC = __expf(eC - SHIFT2);
        float pD = __expf(eD - SHIFT2);
        z += (pA + pB) + (pC + pD);
        a0 += pA * rA.x + pB * rB.x + pC * rC.x + pD * rD.x;
        a1 += pA * rA.y + pB * rB.y + pC * rC.y + pD * rD.y;
    }
    for (; j < e1; j += 16) {
        int s = bdata[j];
        float2 r = rec2[s];
        float e = r.x * ws0 + r.y * ws1 + sdvn;
        e = (e > 0.f) ? e : NEG_SLOPE * e;
        float p = __expf(e - SHIFT2);
        z += p; a0 += p * r.x; a1 += p * r.y;
    }

#pragma unroll
    for (int off = 1; off < 16; off <<= 1) {
        z  += __shfl_xor(z, off);
        a0 += __shfl_xor(a0, off);
        a1 += __shfl_xor(a1, off);
    }

    if (q == 0) {
        float inv = 1.f / (z + 1e-16f);
        float o0 = a0 * inv + b2[0];
        float o1 = a1 * inv + b2[1];
        float mx = fmaxf(o0, o1);
        float lse = mx + __logf(__expf(o0 - mx) + __expf(o1 - mx));
        ((float2*)out)[n] = make_float2(o0 - lse, o1 - lse);
    }
}

// ---------------- host launch ----------------------------------------------
extern "C" void kernel_launch(void* const* d_in, const int* in_sizes, int n_in,
                              void* d_out, int out_size, void* d_ws, size_t ws_size,
                              hipStream_t stream) {
    const float* x   = (const float*)d_in[0];
    const float* W1  = (const float*)d_in[1];
    const float* a1s = (const float*)d_in[2];
    const float* a1d = (const float*)d_in[3];
    const float* b1  = (const float*)d_in[4];
    const float* W2  = (const float*)d_in[5];
    const float* a2s = (const float*)d_in[6];
    const float* a2d = (const float*)d_in[7];
    const float* b2  = (const float*)d_in[8];
    const int*   ei  = (const int*)d_in[9];
    const int* src = ei;
    const int* dst = ei + N_EDGES;

    char* ws = (char*)d_ws;
    uint4*  rec1  = (uint4*) (ws + 0);             // 1,600,000 (100000 x 16B)
    float*  s1d   = (float*) (ws + 1600000);       //   400,000
    float2* rec2  = (float2*)(ws + 2000000);       //   800,000 (100000 x 8B)
    int*    nptr  = (int*)   (ws + 2800000);       //   400,016
    int*    ccnt  = (int*)   (ws + 3200064);       //     1,564 -> pad
    int*    cbase = (int*)   (ws + 3201664);       //     1,568 -> pad
    int*    cursC = (int*)   (ws + 3203264);       //    25,024 (391 x 16 ints, 64B stride)
    unsigned int* bdata = (unsigned int*)(ws + 3228288);  // 25,600,000

    float* out = (float*)d_out;

    hipMemsetAsync(ccnt, 0, NBC * sizeof(int), stream);

    k0_node<<<(N_NODES + 255) / 256, 256, 0, stream>>>(x, W1, a1d, dst, rec1, s1d, ccnt);
    k2b_cscan<<<1, 512, 0, stream>>>(ccnt, cbase, cursC);
    kA_stage<<<NSTG, 1024, 0, stream>>>(src, dst, cursC, bdata);
    kB_sort<<<NBC, 512, 0, stream>>>(cbase, bdata, nptr);
    kAgg1<<<(N_NODES * 16 + 255) / 256, 256, 0, stream>>>(nptr, bdata, rec1, s1d, a1s,
                                                          b1, W2, a2s, a2d, rec2);
    kAgg2<<<(N_NODES * 16 + 255) / 256, 256, 0, stream>>>(nptr, bdata, rec2,
                                                          a2s, a2d, b2, out);
}

// Round 17
// 150.854 us; speedup vs baseline: 1.3851x; 1.1761x over previous
//
#include <hip/hip_runtime.h>
#include <hip/hip_fp16.h>
#include <math.h>

#define N_NODES 100000
#define N_EDGES 6400000
#define F_IN 36
#define HID 8
#define NCLS 2
#define NEG_SLOPE 0.2f

#define COARSE 256                        // nodes per coarse bucket (dst >> 8)
#define NBC 391                           // ceil(N_NODES/256)
#define CAPC 18432                        // max edges per coarse bucket
#define CHUNK 8192                        // edges per scatter chunk
#define NSTG ((N_EDGES + CHUNK - 1) / CHUNK)   // 782
#define SHIFT1 8.0f                       // softmax shift (softmax is shift-invariant)
#define SHIFT2 16.0f

static __device__ __forceinline__ unsigned pack2h(float a, float b) {
    __half2 h = __float22half2_rn(make_float2(a, b));
    return *reinterpret_cast<unsigned*>(&h);
}
static __device__ __forceinline__ float2 unpack2h(unsigned u) {
    __half2 h = *reinterpret_cast<__half2*>(&u);
    return __half22float2(h);
}

// ------- K0: per-node rec1 (fp16 h) + s1d (no histogram) -------------------
__global__ __launch_bounds__(256) void k0_node(
    const float* __restrict__ x, const float* __restrict__ W1,
    const float* __restrict__ a1d_g,
    uint4* __restrict__ rec1, float* __restrict__ s1d)
{
    __shared__ float sW[F_IN * HID];
    __shared__ float sad[HID];
    int tid = threadIdx.x;
    for (int i = tid; i < F_IN * HID; i += 256) sW[i] = W1[i];
    if (tid < HID) sad[tid] = a1d_g[tid];
    __syncthreads();

    int n = blockIdx.x * 256 + tid;
    if (n >= N_NODES) return;

    const float4* xp = (const float4*)(x + (size_t)n * F_IN);
    float h[HID];
#pragma unroll
    for (int f = 0; f < HID; ++f) h[f] = 0.f;
#pragma unroll
    for (int q = 0; q < F_IN / 4; ++q) {
        float4 v = xp[q];
        float vs[4] = {v.x, v.y, v.z, v.w};
#pragma unroll
        for (int j = 0; j < 4; ++j) {
            int k = q * 4 + j;
#pragma unroll
            for (int f = 0; f < HID; ++f) h[f] = fmaf(vs[j], sW[k * HID + f], h[f]);
        }
    }
    float sd = 0.f;
#pragma unroll
    for (int f = 0; f < HID; ++f) sd = fmaf(h[f], sad[f], sd);

    uint4 w;
    w.x = pack2h(h[0], h[1]);
    w.y = pack2h(h[2], h[3]);
    w.z = pack2h(h[4], h[5]);
    w.w = pack2h(h[6], h[7]);
    rec1[n] = w;
    s1d[n] = sd;
}

// ------- KH: per-chunk bucket histogram -> gcnt[g][b] (coalesced) ----------
__global__ __launch_bounds__(256) void kH_hist(const int* __restrict__ dst,
                                               int* __restrict__ gcnt)
{
    __shared__ int lh[NBC];
    int tid = threadIdx.x, g = blockIdx.x;
    for (int i = tid; i < NBC; i += 256) lh[i] = 0;
    __syncthreads();

    int e0 = g * CHUNK;
    int ne = N_EDGES - e0; if (ne > CHUNK) ne = CHUNK;
    int n4 = ne >> 2;
    const int4* dv = (const int4*)(dst + e0);
    for (int i = tid; i < n4; i += 256) {
        int4 d = dv[i];
        atomicAdd(&lh[d.x >> 8], 1);
        atomicAdd(&lh[d.y >> 8], 1);
        atomicAdd(&lh[d.z >> 8], 1);
        atomicAdd(&lh[d.w >> 8], 1);
    }
    __syncthreads();
    for (int i = tid; i < NBC; i += 256) gcnt[(size_t)g * NBC + i] = lh[i];
}

// ------- KS: per-bucket exclusive scan over chunks -> lpre[b][g], tot[b] ---
__global__ __launch_bounds__(256) void kS_scan(const int* __restrict__ gcnt,
                                               int* __restrict__ lpre, int* __restrict__ tot)
{
    __shared__ int sv[256];
    int b = blockIdx.x, tid = threadIdx.x;
    int carry = 0;
    const int ntile = (NSTG + 255) / 256;
    for (int t = 0; t < ntile; ++t) {
        int g = t * 256 + tid;
        int v = (g < NSTG) ? gcnt[(size_t)g * NBC + b] : 0;
        sv[tid] = v;
        __syncthreads();
        for (int off = 1; off < 256; off <<= 1) {
            int x = (tid >= off) ? sv[tid - off] : 0;
            __syncthreads();
            sv[tid] += x;
            __syncthreads();
        }
        if (g < NSTG) lpre[(size_t)b * NSTG + g] = carry + sv[tid] - v;
        carry += sv[255];
        __syncthreads();
    }
    if (tid == 0) tot[b] = carry;
}

// ------- K2b: scan bucket totals -> cbase ----------------------------------
__global__ __launch_bounds__(512) void k2b_cscan(const int* __restrict__ tot,
                                                 int* __restrict__ cbase)
{
    __shared__ int s[512];
    int tid = threadIdx.x;
    int v = (tid < NBC) ? tot[tid] : 0;
    s[tid] = v;
    __syncthreads();
    for (int off = 1; off < 512; off <<= 1) {
        int t = (tid >= off) ? s[tid - off] : 0;
        __syncthreads();
        s[tid] += t;
        __syncthreads();
    }
    int ex = s[tid] - v;
    if (tid < NBC) cbase[tid] = ex;
    if (tid == NBC) cbase[NBC] = ex;   // == N_EDGES
}

// ------- KA: staged scatter — NO global atomics (precomputed offsets) ------
__global__ __launch_bounds__(1024) void kA_stage(
    const int* __restrict__ src, const int* __restrict__ dst,
    const int* __restrict__ cbase, const int* __restrict__ lpre,
    unsigned int* __restrict__ bdata)
{
    __shared__ unsigned int stg[CHUNK];          // 32 KB
    __shared__ unsigned short aux[CHUNK];        // 16 KB
    __shared__ int lh[NBC];
    __shared__ int lstart[NBC];
    __shared__ int lcur[NBC];
    __shared__ int tbase[NBC];
    int tid = threadIdx.x, g = blockIdx.x;

    for (int i = tid; i < NBC; i += 1024) lh[i] = 0;
    __syncthreads();

    int e0 = g * CHUNK;
    int ne = N_EDGES - e0; if (ne > CHUNK) ne = CHUNK;   // multiple of 4
    int n4 = ne >> 2;
    const int4* dv = (const int4*)(dst + e0);
    const int4* sv = (const int4*)(src + e0);

    // pass 1: load chunk into registers + histogram (2 int4 per thread)
    int4 d0, s0, d1, s1;
    bool v0 = (tid < n4), v1 = (tid + 1024 < n4);
    if (v0) {
        d0 = dv[tid]; s0 = sv[tid];
        atomicAdd(&lh[d0.x >> 8], 1);
        atomicAdd(&lh[d0.y >> 8], 1);
        atomicAdd(&lh[d0.z >> 8], 1);
        atomicAdd(&lh[d0.w >> 8], 1);
    }
    if (v1) {
        d1 = dv[tid + 1024]; s1 = sv[tid + 1024];
        atomicAdd(&lh[d1.x >> 8], 1);
        atomicAdd(&lh[d1.y >> 8], 1);
        atomicAdd(&lh[d1.z >> 8], 1);
        atomicAdd(&lh[d1.w >> 8], 1);
    }
    __syncthreads();

    // wave-0 exclusive scan of 391 counts (7 per lane)
    if (tid < 64) {
        int base = tid * 7;
        int cnt[7];
        int s = 0;
#pragma unroll
        for (int k = 0; k < 7; ++k) {
            int b = base + k;
            cnt[k] = (b < NBC) ? lh[b] : 0;
            s += cnt[k];
        }
        int inc = s;
#pragma unroll
        for (int off = 1; off < 64; off <<= 1) {
            int t2 = __shfl_up(inc, off);
            if (tid >= off) inc += t2;
        }
        int ex = inc - s;
#pragma unroll
        for (int k = 0; k < 7; ++k) {
            int b = base + k;
            if (b < NBC) { lstart[b] = ex; lcur[b] = ex; ex += cnt[k]; }
        }
    }
    __syncthreads();

    // global offsets: plain loads, zero atomics
    for (int b = tid; b < NBC; b += 1024) {
        tbase[b] = cbase[b] + lpre[(size_t)b * NSTG + g];
    }

    // pass 2: scatter registers into LDS bucket order (+ record bucket id)
    if (v0) {
        int b, p;
        b = d0.x >> 8; p = atomicAdd(&lcur[b], 1); stg[p] = (unsigned)s0.x | ((unsigned)(d0.x & 255) << 17); aux[p] = (unsigned short)b;
        b = d0.y >> 8; p = atomicAdd(&lcur[b], 1); stg[p] = (unsigned)s0.y | ((unsigned)(d0.y & 255) << 17); aux[p] = (unsigned short)b;
        b = d0.z >> 8; p = atomicAdd(&lcur[b], 1); stg[p] = (unsigned)s0.z | ((unsigned)(d0.z & 255) << 17); aux[p] = (unsigned short)b;
        b = d0.w >> 8; p = atomicAdd(&lcur[b], 1); stg[p] = (unsigned)s0.w | ((unsigned)(d0.w & 255) << 17); aux[p] = (unsigned short)b;
    }
    if (v1) {
        int b, p;
        b = d1.x >> 8; p = atomicAdd(&lcur[b], 1); stg[p] = (unsigned)s1.x | ((unsigned)(d1.x & 255) << 17); aux[p] = (unsigned short)b;
        b = d1.y >> 8; p = atomicAdd(&lcur[b], 1); stg[p] = (unsigned)s1.y | ((unsigned)(d1.y & 255) << 17); aux[p] = (unsigned short)b;
        b = d1.z >> 8; p = atomicAdd(&lcur[b], 1); stg[p] = (unsigned)s1.z | ((unsigned)(d1.z & 255) << 17); aux[p] = (unsigned short)b;
        b = d1.w >> 8; p = atomicAdd(&lcur[b], 1); stg[p] = (unsigned)s1.w | ((unsigned)(d1.w & 255) << 17); aux[p] = (unsigned short)b;
    }
    __syncthreads();

    // flush: every lane active; runs stay contiguous -> coalesced
    for (int i = tid; i < ne; i += 1024) {
        int bb = aux[i];
        bdata[tbase[bb] + (i - lstart[bb])] = stg[i];
    }
}

// ------- KB: in-LDS node-granularity sort; emits nptr CSR (512T) -----------
__global__ __launch_bounds__(512) void kB_sort(
    const int* __restrict__ cbase, unsigned int* __restrict__ bdata,
    int* __restrict__ nptr)
{
    __shared__ unsigned int raw[CAPC];    // 72 KB
    __shared__ int cnt[COARSE];
    __shared__ int sstart[COARSE];
    __shared__ int cur[COARSE];
    int tid = threadIdx.x;
    int c = blockIdx.x;
    int cb0 = cbase[c], cb1 = cbase[c + 1];
    int ne = cb1 - cb0;

    if (tid < COARSE) cnt[tid] = 0;
    __syncthreads();

    for (int i = tid; i < ne; i += 512) {
        unsigned pk = bdata[cb0 + i];
        raw[i] = pk;
        atomicAdd(&cnt[pk >> 17], 1);
    }
    __syncthreads();

    if (tid < 64) {
        int base = tid * 4;
        int c0 = cnt[base], c1 = cnt[base + 1], c2 = cnt[base + 2], c3 = cnt[base + 3];
        int s = c0 + c1 + c2 + c3;
        int inc = s;
#pragma unroll
        for (int off = 1; off < 64; off <<= 1) {
            int t2 = __shfl_up(inc, off);
            if (tid >= off) inc += t2;
        }
        int ex = inc - s;
        sstart[base]     = ex; cur[base]     = ex; ex += c0;
        sstart[base + 1] = ex; cur[base + 1] = ex; ex += c1;
        sstart[base + 2] = ex; cur[base + 2] = ex; ex += c2;
        sstart[base + 3] = ex; cur[base + 3] = ex;
    }
    __syncthreads();

    if (tid < COARSE) {
        int nid = c * COARSE + tid;
        if (nid < N_NODES) nptr[nid] = cb0 + sstart[tid];
    }
    if (c == 0 && tid == 0) nptr[N_NODES] = N_EDGES;

    for (int i = tid; i < ne; i += 512) {
        unsigned pk = raw[i];
        int loc = pk >> 17;
        int p = atomicAdd(&cur[loc], 1);
        bdata[cb0 + p] = pk & 0x1FFFF;    // node-sorted: store src only
    }
}

// ---------------- KAgg1: layer-1 agg, ONE uint4 gather per edge ------------
__global__ __launch_bounds__(256) void kAgg1(
    const int* __restrict__ nptr, const unsigned int* __restrict__ bdata,
    const uint4* __restrict__ rec1, const float* __restrict__ s1d,
    const float* __restrict__ a1s_g,
    const float* __restrict__ b1, const float* __restrict__ W2,
    float2* __restrict__ rec2)
{
    int gi = blockIdx.x * 256 + threadIdx.x;
    int n = gi >> 4, q = gi & 15;
    if (n >= N_NODES) return;

    float as0 = a1s_g[0], as1 = a1s_g[1], as2 = a1s_g[2], as3 = a1s_g[3];
    float as4 = a1s_g[4], as5 = a1s_g[5], as6 = a1s_g[6], as7 = a1s_g[7];

    int e0 = nptr[n], e1 = nptr[n + 1];
    float sdvn = s1d[n];
    float z = 0.f;
    float acc[HID];
#pragma unroll
    for (int f = 0; f < HID; ++f) acc[f] = 0.f;

    int j = e0 + q;
    for (; j + 48 < e1; j += 64) {
        int sA = bdata[j], sB = bdata[j + 16], sC = bdata[j + 32], sD = bdata[j + 48];
        uint4 ha = rec1[sA];
        uint4 hb = rec1[sB];
        uint4 hc = rec1[sC];
        uint4 hd = rec1[sD];
        float2 fa01 = unpack2h(ha.x), fa23 = unpack2h(ha.y), fa45 = unpack2h(ha.z), fa67 = unpack2h(ha.w);
        float2 fb01 = unpack2h(hb.x), fb23 = unpack2h(hb.y), fb45 = unpack2h(hb.z), fb67 = unpack2h(hb.w);
        float2 fc01 = unpack2h(hc.x), fc23 = unpack2h(hc.y), fc45 = unpack2h(hc.z), fc67 = unpack2h(hc.w);
        float2 fd01 = unpack2h(hd.x), fd23 = unpack2h(hd.y), fd45 = unpack2h(hd.z), fd67 = unpack2h(hd.w);
        float ssA = fa01.x*as0 + fa01.y*as1 + fa23.x*as2 + fa23.y*as3
                  + fa45.x*as4 + fa45.y*as5 + fa67.x*as6 + fa67.y*as7;
        float ssB = fb01.x*as0 + fb01.y*as1 + fb23.x*as2 + fb23.y*as3
                  + fb45.x*as4 + fb45.y*as5 + fb67.x*as6 + fb67.y*as7;
        float ssC = fc01.x*as0 + fc01.y*as1 + fc23.x*as2 + fc23.y*as3
                  + fc45.x*as4 + fc45.y*as5 + fc67.x*as6 + fc67.y*as7;
        float ssD = fd01.x*as0 + fd01.y*as1 + fd23.x*as2 + fd23.y*as3
                  + fd45.x*as4 + fd45.y*as5 + fd67.x*as6 + fd67.y*as7;
        float eA = ssA + sdvn; eA = (eA > 0.f) ? eA : NEG_SLOPE * eA;
        float eB = ssB + sdvn; eB = (eB > 0.f) ? eB : NEG_SLOPE * eB;
        float eC = ssC + sdvn; eC = (eC > 0.f) ? eC : NEG_SLOPE * eC;
        float eD = ssD + sdvn; eD = (eD > 0.f) ? eD : NEG_SLOPE * eD;
        float pA = __expf(eA - SHIFT1);
        float pB = __expf(eB - SHIFT1);
        float pC = __expf(eC - SHIFT1);
        float pD = __expf(eD - SHIFT1);
        z += (pA + pB) + (pC + pD);
        acc[0] += pA * fa01.x + pB * fb01.x + pC * fc01.x + pD * fd01.x;
        acc[1] += pA * fa01.y + pB * fb01.y + pC * fc01.y + pD * fd01.y;
        acc[2] += pA * fa23.x + pB * fb23.x + pC * fc23.x + pD * fd23.x;
        acc[3] += pA * fa23.y + pB * fb23.y + pC * fc23.y + pD * fd23.y;
        acc[4] += pA * fa45.x + pB * fb45.x + pC * fc45.x + pD * fd45.x;
        acc[5] += pA * fa45.y + pB * fb45.y + pC * fc45.y + pD * fd45.y;
        acc[6] += pA * fa67.x + pB * fb67.x + pC * fc67.x + pD * fd67.x;
        acc[7] += pA * fa67.y + pB * fb67.y + pC * fc67.y + pD * fd67.y;
    }
    for (; j < e1; j += 16) {
        int s = bdata[j];
        uint4 hv = rec1[s];
        float2 f01 = unpack2h(hv.x), f23 = unpack2h(hv.y);
        float2 f45 = unpack2h(hv.z), f67 = unpack2h(hv.w);
        float ss = f01.x*as0 + f01.y*as1 + f23.x*as2 + f23.y*as3
                 + f45.x*as4 + f45.y*as5 + f67.x*as6 + f67.y*as7;
        float e = ss + sdvn;
        e = (e > 0.f) ? e : NEG_SLOPE * e;
        float p = __expf(e - SHIFT1);
        z += p;
        acc[0] += p * f01.x; acc[1] += p * f01.y;
        acc[2] += p * f23.x; acc[3] += p * f23.y;
        acc[4] += p * f45.x; acc[5] += p * f45.y;
        acc[6] += p * f67.x; acc[7] += p * f67.y;
    }

#pragma unroll
    for (int off = 1; off < 16; off <<= 1) {
        z += __shfl_xor(z, off);
#pragma unroll
        for (int f = 0; f < HID; ++f) acc[f] += __shfl_xor(acc[f], off);
    }

    if (q == 0) {
        float inv = 1.f / (z + 1e-16f);
        float c0 = 0.f, c1 = 0.f;
#pragma unroll
        for (int f = 0; f < HID; ++f) {
            float hr = fmaxf(acc[f] * inv + b1[f], 0.f);
            c0 = fmaf(hr, W2[f * NCLS + 0], c0);
            c1 = fmaf(hr, W2[f * NCLS + 1], c1);
        }
        rec2[n] = make_float2(c0, c1);
    }
}

// ---------------- KAgg2: layer-2 agg, ONE float2 gather per edge -----------
__global__ __launch_bounds__(256) void kAgg2(
    const int* __restrict__ nptr, const unsigned int* __restrict__ bdata,
    const float2* __restrict__ rec2,
    const float* __restrict__ a2s, const float* __restrict__ a2d,
    const float* __restrict__ b2, float* __restrict__ out)
{
    int gi = blockIdx.x * 256 + threadIdx.x;
    int n = gi >> 4, q = gi & 15;
    if (n >= N_NODES) return;

    float ws0 = a2s[0], ws1 = a2s[1];
    float wd0 = a2d[0], wd1 = a2d[1];

    int e0 = nptr[n], e1 = nptr[n + 1];
    float2 rn = rec2[n];
    float sdvn = rn.x * wd0 + rn.y * wd1;
    float z = 0.f, a0 = 0.f, a1 = 0.f;

    int j = e0 + q;
    for (; j + 48 < e1; j += 64) {
        int sA = bdata[j];
        int sB = bdata[j + 16];
        int sC = bdata[j + 32];
        int sD = bdata[j + 48];
        float2 rA = rec2[sA];
        float2 rB = rec2[sB];
        float2 rC = rec2[sC];
        float2 rD = rec2[sD];
        float eA = rA.x * ws0 + rA.y * ws1 + sdvn; eA = (eA > 0.f) ? eA : NEG_SLOPE * eA;
        float eB = rB.x * ws0 + rB.y * ws1 + sdvn; eB = (eB > 0.f) ? eB : NEG_SLOPE * eB;
        float eC = rC.x * ws0 + rC.y * ws1 + sdvn; eC = (eC > 0.f) ? eC : NEG_SLOPE * eC;
        float eD = rD.x * ws0 + rD.y * ws1 + sdvn; eD = (eD > 0.f) ? eD : NEG_SLOPE * eD;
        float pA = __expf(eA - SHIFT2);
        float pB = __expf(eB - SHIFT2);
        float pC = __expf(eC - SHIFT2);
        float pD = __expf(eD - SHIFT2);
        z += (pA + pB) + (pC + pD);
        a0 += pA * rA.x + pB * rB.x + pC * rC.x + pD * rD.x;
        a1 += pA * rA.y + pB * rB.y + pC * rC.y + pD * rD.y;
    }
    for (; j < e1; j += 16) {
        int s = bdata[j];
        float2 r = rec2[s];
        float e = r.x * ws0 + r.y * ws1 + sdvn;
        e = (e > 0.f) ? e : NEG_SLOPE * e;
        float p = __expf(e - SHIFT2);
        z += p; a0 += p * r.x; a1 += p * r.y;
    }

#pragma unroll
    for (int off = 1; off < 16; off <<= 1) {
        z  += __shfl_xor(z, off);
        a0 += __shfl_xor(a0, off);
        a1 += __shfl_xor(a1, off);
    }

    if (q == 0) {
        float inv = 1.f / (z + 1e-16f);
        float o0 = a0 * inv + b2[0];
        float o1 = a1 * inv + b2[1];
        float mx = fmaxf(o0, o1);
        float lse = mx + __logf(__expf(o0 - mx) + __expf(o1 - mx));
        ((float2*)out)[n] = make_float2(o0 - lse, o1 - lse);
    }
}

// ---------------- host launch ----------------------------------------------
extern "C" void kernel_launch(void* const* d_in, const int* in_sizes, int n_in,
                              void* d_out, int out_size, void* d_ws, size_t ws_size,
                              hipStream_t stream) {
    const float* x   = (const float*)d_in[0];
    const float* W1  = (const float*)d_in[1];
    const float* a1s = (const float*)d_in[2];
    const float* a1d = (const float*)d_in[3];
    const float* b1  = (const float*)d_in[4];
    const float* W2  = (const float*)d_in[5];
    const float* a2s = (const float*)d_in[6];
    const float* a2d = (const float*)d_in[7];
    const float* b2  = (const float*)d_in[8];
    const int*   ei  = (const int*)d_in[9];
    const int* src = ei;
    const int* dst = ei + N_EDGES;

    char* ws = (char*)d_ws;
    uint4*  rec1  = (uint4*) (ws + 0);              // 1,600,000 (100000 x 16B)
    float*  s1d   = (float*) (ws + 1600000);        //   400,000
    float2* rec2  = (float2*)(ws + 2000000);        //   800,000
    int*    nptr  = (int*)   (ws + 2800000);        //   400,016
    int*    cbase = (int*)   (ws + 3200064);        //     1,568 -> pad
    int*    tot   = (int*)   (ws + 3201664);        //     1,564 -> pad
    unsigned int* bdata = (unsigned int*)(ws + 3203264);  // 25,600,000 -> ends 28,803,264
    int*    gcnt  = (int*)   (ws + 28803264);       // 782x391x4 = 1,223,048
    int*    lpre  = (int*)   (ws + 30026312);       // 391x782x4 = 1,223,048 -> ends 31,249,360

    float* out = (float*)d_out;

    k0_node<<<(N_NODES + 255) / 256, 256, 0, stream>>>(x, W1, a1d, rec1, s1d);
    kH_hist<<<NSTG, 256, 0, stream>>>(dst, gcnt);
    kS_scan<<<NBC, 256, 0, stream>>>(gcnt, lpre, tot);
    k2b_cscan<<<1, 512, 0, stream>>>(tot, cbase);
    kA_stage<<<NSTG, 1024, 0, stream>>>(src, dst, cbase, lpre, bdata);
    kB_sort<<<NBC, 512, 0, stream>>>(cbase, bdata, nptr);
    kAgg1<<<(N_NODES * 16 + 255) / 256, 256, 0, stream>>>(nptr, bdata, rec1, s1d, a1s,
                                                          b1, W2, rec2);
    kAgg2<<<(N_NODES * 16 + 255) / 256, 256, 0, stream>>>(nptr, bdata, rec2,
                                                          a2s, a2d, b2, out);
}

// Round 18
// 146.973 us; speedup vs baseline: 1.4216x; 1.0264x over previous
//
#include <hip/hip_runtime.h>
#include <hip/hip_fp16.h>
#include <math.h>

#define N_NODES 100000
#define N_EDGES 6400000
#define F_IN 36
#define HID 8
#define NCLS 2
#define NEG_SLOPE 0.2f

#define COARSE 256                        // nodes per coarse bucket (dst >> 8)
#define NBC 391                           // ceil(N_NODES/256)
#define CAPC 18432                        // max edges per coarse bucket
#define CHUNK 8192                        // edges per scatter chunk
#define NSTG ((N_EDGES + CHUNK - 1) / CHUNK)   // 782
#define SHIFT1 8.0f                       // softmax shift (softmax is shift-invariant)
#define SHIFT2 16.0f

static __device__ __forceinline__ unsigned pack2h(float a, float b) {
    __half2 h = __float22half2_rn(make_float2(a, b));
    return *reinterpret_cast<unsigned*>(&h);
}
static __device__ __forceinline__ float2 unpack2h(unsigned u) {
    __half2 h = *reinterpret_cast<__half2*>(&u);
    return __half22float2(h);
}

// ------- K0: per-node rec1 (fp16 h) + s1d (no histogram) -------------------
__global__ __launch_bounds__(256) void k0_node(
    const float* __restrict__ x, const float* __restrict__ W1,
    const float* __restrict__ a1d_g,
    uint4* __restrict__ rec1, float* __restrict__ s1d)
{
    __shared__ float sW[F_IN * HID];
    __shared__ float sad[HID];
    int tid = threadIdx.x;
    for (int i = tid; i < F_IN * HID; i += 256) sW[i] = W1[i];
    if (tid < HID) sad[tid] = a1d_g[tid];
    __syncthreads();

    int n = blockIdx.x * 256 + tid;
    if (n >= N_NODES) return;

    const float4* xp = (const float4*)(x + (size_t)n * F_IN);
    float h[HID];
#pragma unroll
    for (int f = 0; f < HID; ++f) h[f] = 0.f;
#pragma unroll
    for (int q = 0; q < F_IN / 4; ++q) {
        float4 v = xp[q];
        float vs[4] = {v.x, v.y, v.z, v.w};
#pragma unroll
        for (int j = 0; j < 4; ++j) {
            int k = q * 4 + j;
#pragma unroll
            for (int f = 0; f < HID; ++f) h[f] = fmaf(vs[j], sW[k * HID + f], h[f]);
        }
    }
    float sd = 0.f;
#pragma unroll
    for (int f = 0; f < HID; ++f) sd = fmaf(h[f], sad[f], sd);

    uint4 w;
    w.x = pack2h(h[0], h[1]);
    w.y = pack2h(h[2], h[3]);
    w.z = pack2h(h[4], h[5]);
    w.w = pack2h(h[6], h[7]);
    rec1[n] = w;
    s1d[n] = sd;
}

// ------- KH: per-chunk bucket histogram -> gcnt[g][b] (coalesced) ----------
__global__ __launch_bounds__(256) void kH_hist(const int* __restrict__ dst,
                                               int* __restrict__ gcnt)
{
    __shared__ int lh[NBC];
    int tid = threadIdx.x, g = blockIdx.x;
    for (int i = tid; i < NBC; i += 256) lh[i] = 0;
    __syncthreads();

    int e0 = g * CHUNK;
    int ne = N_EDGES - e0; if (ne > CHUNK) ne = CHUNK;
    int n4 = ne >> 2;
    const int4* dv = (const int4*)(dst + e0);
    for (int i = tid; i < n4; i += 256) {
        int4 d = dv[i];
        atomicAdd(&lh[d.x >> 8], 1);
        atomicAdd(&lh[d.y >> 8], 1);
        atomicAdd(&lh[d.z >> 8], 1);
        atomicAdd(&lh[d.w >> 8], 1);
    }
    __syncthreads();
    for (int i = tid; i < NBC; i += 256) gcnt[(size_t)g * NBC + i] = lh[i];
}

// ------- KS: per-bucket exclusive scan over chunks -> lpre[b][g], tot[b] ---
__global__ __launch_bounds__(256) void kS_scan(const int* __restrict__ gcnt,
                                               int* __restrict__ lpre, int* __restrict__ tot)
{
    __shared__ int sv[256];
    int b = blockIdx.x, tid = threadIdx.x;
    int carry = 0;
    const int ntile = (NSTG + 255) / 256;
    for (int t = 0; t < ntile; ++t) {
        int g = t * 256 + tid;
        int v = (g < NSTG) ? gcnt[(size_t)g * NBC + b] : 0;
        sv[tid] = v;
        __syncthreads();
        for (int off = 1; off < 256; off <<= 1) {
            int x = (tid >= off) ? sv[tid - off] : 0;
            __syncthreads();
            sv[tid] += x;
            __syncthreads();
        }
        if (g < NSTG) lpre[(size_t)b * NSTG + g] = carry + sv[tid] - v;
        carry += sv[255];
        __syncthreads();
    }
    if (tid == 0) tot[b] = carry;
}

// ------- K2b: scan bucket totals -> cbase ----------------------------------
__global__ __launch_bounds__(512) void k2b_cscan(const int* __restrict__ tot,
                                                 int* __restrict__ cbase)
{
    __shared__ int s[512];
    int tid = threadIdx.x;
    int v = (tid < NBC) ? tot[tid] : 0;
    s[tid] = v;
    __syncthreads();
    for (int off = 1; off < 512; off <<= 1) {
        int t = (tid >= off) ? s[tid - off] : 0;
        __syncthreads();
        s[tid] += t;
        __syncthreads();
    }
    int ex = s[tid] - v;
    if (tid < NBC) cbase[tid] = ex;
    if (tid == NBC) cbase[NBC] = ex;   // == N_EDGES
}

// ------- KA: staged scatter — NO global atomics (precomputed offsets) ------
__global__ __launch_bounds__(1024) void kA_stage(
    const int* __restrict__ src, const int* __restrict__ dst,
    const int* __restrict__ cbase, const int* __restrict__ lpre,
    unsigned int* __restrict__ bdata)
{
    __shared__ unsigned int stg[CHUNK];          // 32 KB
    __shared__ unsigned short aux[CHUNK];        // 16 KB
    __shared__ int lh[NBC];
    __shared__ int lstart[NBC];
    __shared__ int lcur[NBC];
    __shared__ int tbase[NBC];
    int tid = threadIdx.x, g = blockIdx.x;

    for (int i = tid; i < NBC; i += 1024) lh[i] = 0;
    __syncthreads();

    int e0 = g * CHUNK;
    int ne = N_EDGES - e0; if (ne > CHUNK) ne = CHUNK;   // multiple of 4
    int n4 = ne >> 2;
    const int4* dv = (const int4*)(dst + e0);
    const int4* sv = (const int4*)(src + e0);

    // pass 1: load chunk into registers + histogram (2 int4 per thread)
    int4 d0, s0, d1, s1;
    bool v0 = (tid < n4), v1 = (tid + 1024 < n4);
    if (v0) {
        d0 = dv[tid]; s0 = sv[tid];
        atomicAdd(&lh[d0.x >> 8], 1);
        atomicAdd(&lh[d0.y >> 8], 1);
        atomicAdd(&lh[d0.z >> 8], 1);
        atomicAdd(&lh[d0.w >> 8], 1);
    }
    if (v1) {
        d1 = dv[tid + 1024]; s1 = sv[tid + 1024];
        atomicAdd(&lh[d1.x >> 8], 1);
        atomicAdd(&lh[d1.y >> 8], 1);
        atomicAdd(&lh[d1.z >> 8], 1);
        atomicAdd(&lh[d1.w >> 8], 1);
    }
    __syncthreads();

    // wave-0 exclusive scan of 391 counts (7 per lane)
    if (tid < 64) {
        int base = tid * 7;
        int cnt[7];
        int s = 0;
#pragma unroll
        for (int k = 0; k < 7; ++k) {
            int b = base + k;
            cnt[k] = (b < NBC) ? lh[b] : 0;
            s += cnt[k];
        }
        int inc = s;
#pragma unroll
        for (int off = 1; off < 64; off <<= 1) {
            int t2 = __shfl_up(inc, off);
            if (tid >= off) inc += t2;
        }
        int ex = inc - s;
#pragma unroll
        for (int k = 0; k < 7; ++k) {
            int b = base + k;
            if (b < NBC) { lstart[b] = ex; lcur[b] = ex; ex += cnt[k]; }
        }
    }
    __syncthreads();

    // global offsets: plain loads, zero atomics
    for (int b = tid; b < NBC; b += 1024) {
        tbase[b] = cbase[b] + lpre[(size_t)b * NSTG + g];
    }

    // pass 2: scatter registers into LDS bucket order (+ record bucket id)
    if (v0) {
        int b, p;
        b = d0.x >> 8; p = atomicAdd(&lcur[b], 1); stg[p] = (unsigned)s0.x | ((unsigned)(d0.x & 255) << 17); aux[p] = (unsigned short)b;
        b = d0.y >> 8; p = atomicAdd(&lcur[b], 1); stg[p] = (unsigned)s0.y | ((unsigned)(d0.y & 255) << 17); aux[p] = (unsigned short)b;
        b = d0.z >> 8; p = atomicAdd(&lcur[b], 1); stg[p] = (unsigned)s0.z | ((unsigned)(d0.z & 255) << 17); aux[p] = (unsigned short)b;
        b = d0.w >> 8; p = atomicAdd(&lcur[b], 1); stg[p] = (unsigned)s0.w | ((unsigned)(d0.w & 255) << 17); aux[p] = (unsigned short)b;
    }
    if (v1) {
        int b, p;
        b = d1.x >> 8; p = atomicAdd(&lcur[b], 1); stg[p] = (unsigned)s1.x | ((unsigned)(d1.x & 255) << 17); aux[p] = (unsigned short)b;
        b = d1.y >> 8; p = atomicAdd(&lcur[b], 1); stg[p] = (unsigned)s1.y | ((unsigned)(d1.y & 255) << 17); aux[p] = (unsigned short)b;
        b = d1.z >> 8; p = atomicAdd(&lcur[b], 1); stg[p] = (unsigned)s1.z | ((unsigned)(d1.z & 255) << 17); aux[p] = (unsigned short)b;
        b = d1.w >> 8; p = atomicAdd(&lcur[b], 1); stg[p] = (unsigned)s1.w | ((unsigned)(d1.w & 255) << 17); aux[p] = (unsigned short)b;
    }
    __syncthreads();

    // flush: every lane active; runs stay contiguous -> coalesced
    for (int i = tid; i < ne; i += 1024) {
        int bb = aux[i];
        bdata[tbase[bb] + (i - lstart[bb])] = stg[i];
    }
}

// ------- KB: in-LDS node-granularity sort; emits nptr CSR (1024T) ----------
__global__ __launch_bounds__(1024) void kB_sort(
    const int* __restrict__ cbase, unsigned int* __restrict__ bdata,
    int* __restrict__ nptr)
{
    __shared__ unsigned int raw[CAPC];    // 72 KB
    __shared__ int cnt[COARSE];
    __shared__ int sstart[COARSE];
    __shared__ int cur[COARSE];
    int tid = threadIdx.x;
    int c = blockIdx.x;
    int cb0 = cbase[c], cb1 = cbase[c + 1];
    int ne = cb1 - cb0;

    if (tid < COARSE) cnt[tid] = 0;
    __syncthreads();

    for (int i = tid; i < ne; i += 1024) {
        unsigned pk = bdata[cb0 + i];
        raw[i] = pk;
        atomicAdd(&cnt[pk >> 17], 1);
    }
    __syncthreads();

    if (tid < 64) {
        int base = tid * 4;
        int c0 = cnt[base], c1 = cnt[base + 1], c2 = cnt[base + 2], c3 = cnt[base + 3];
        int s = c0 + c1 + c2 + c3;
        int inc = s;
#pragma unroll
        for (int off = 1; off < 64; off <<= 1) {
            int t2 = __shfl_up(inc, off);
            if (tid >= off) inc += t2;
        }
        int ex = inc - s;
        sstart[base]     = ex; cur[base]     = ex; ex += c0;
        sstart[base + 1] = ex; cur[base + 1] = ex; ex += c1;
        sstart[base + 2] = ex; cur[base + 2] = ex; ex += c2;
        sstart[base + 3] = ex; cur[base + 3] = ex;
    }
    __syncthreads();

    if (tid < COARSE) {
        int nid = c * COARSE + tid;
        if (nid < N_NODES) nptr[nid] = cb0 + sstart[tid];
    }
    if (c == 0 && tid == 0) nptr[N_NODES] = N_EDGES;

    for (int i = tid; i < ne; i += 1024) {
        unsigned pk = raw[i];
        int loc = pk >> 17;
        int p = atomicAdd(&cur[loc], 1);
        bdata[cb0 + p] = pk & 0x1FFFF;    // node-sorted: store src only
    }
}

// ---------------- KAgg1: layer-1 agg, ONE uint4 gather per edge ------------
__global__ __launch_bounds__(256) void kAgg1(
    const int* __restrict__ nptr, const unsigned int* __restrict__ bdata,
    const uint4* __restrict__ rec1, const float* __restrict__ s1d,
    const float* __restrict__ a1s_g,
    const float* __restrict__ b1, const float* __restrict__ W2,
    float2* __restrict__ rec2)
{
    int gi = blockIdx.x * 256 + threadIdx.x;
    int n = gi >> 4, q = gi & 15;
    if (n >= N_NODES) return;

    float as0 = a1s_g[0], as1 = a1s_g[1], as2 = a1s_g[2], as3 = a1s_g[3];
    float as4 = a1s_g[4], as5 = a1s_g[5], as6 = a1s_g[6], as7 = a1s_g[7];

    int e0 = nptr[n], e1 = nptr[n + 1];
    float sdvn = s1d[n];
    float z = 0.f;
    float acc[HID];
#pragma unroll
    for (int f = 0; f < HID; ++f) acc[f] = 0.f;

    int j = e0 + q;
    for (; j + 48 < e1; j += 64) {
        int sA = bdata[j], sB = bdata[j + 16], sC = bdata[j + 32], sD = bdata[j + 48];
        uint4 ha = rec1[sA];
        uint4 hb = rec1[sB];
        uint4 hc = rec1[sC];
        uint4 hd = rec1[sD];
        float2 fa01 = unpack2h(ha.x), fa23 = unpack2h(ha.y), fa45 = unpack2h(ha.z), fa67 = unpack2h(ha.w);
        float2 fb01 = unpack2h(hb.x), fb23 = unpack2h(hb.y), fb45 = unpack2h(hb.z), fb67 = unpack2h(hb.w);
        float2 fc01 = unpack2h(hc.x), fc23 = unpack2h(hc.y), fc45 = unpack2h(hc.z), fc67 = unpack2h(hc.w);
        float2 fd01 = unpack2h(hd.x), fd23 = unpack2h(hd.y), fd45 = unpack2h(hd.z), fd67 = unpack2h(hd.w);
        float ssA = fa01.x*as0 + fa01.y*as1 + fa23.x*as2 + fa23.y*as3
                  + fa45.x*as4 + fa45.y*as5 + fa67.x*as6 + fa67.y*as7;
        float ssB = fb01.x*as0 + fb01.y*as1 + fb23.x*as2 + fb23.y*as3
                  + fb45.x*as4 + fb45.y*as5 + fb67.x*as6 + fb67.y*as7;
        float ssC = fc01.x*as0 + fc01.y*as1 + fc23.x*as2 + fc23.y*as3
                  + fc45.x*as4 + fc45.y*as5 + fc67.x*as6 + fc67.y*as7;
        float ssD = fd01.x*as0 + fd01.y*as1 + fd23.x*as2 + fd23.y*as3
                  + fd45.x*as4 + fd45.y*as5 + fd67.x*as6 + fd67.y*as7;
        float eA = ssA + sdvn; eA = (eA > 0.f) ? eA : NEG_SLOPE * eA;
        float eB = ssB + sdvn; eB = (eB > 0.f) ? eB : NEG_SLOPE * eB;
        float eC = ssC + sdvn; eC = (eC > 0.f) ? eC : NEG_SLOPE * eC;
        float eD = ssD + sdvn; eD = (eD > 0.f) ? eD : NEG_SLOPE * eD;
        float pA = __expf(eA - SHIFT1);
        float pB = __expf(eB - SHIFT1);
        float pC = __expf(eC - SHIFT1);
        float pD = __expf(eD - SHIFT1);
        z += (pA + pB) + (pC + pD);
        acc[0] += pA * fa01.x + pB * fb01.x + pC * fc01.x + pD * fd01.x;
        acc[1] += pA * fa01.y + pB * fb01.y + pC * fc01.y + pD * fd01.y;
        acc[2] += pA * fa23.x + pB * fb23.x + pC * fc23.x + pD * fd23.x;
        acc[3] += pA * fa23.y + pB * fb23.y + pC * fc23.y + pD * fd23.y;
        acc[4] += pA * fa45.x + pB * fb45.x + pC * fc45.x + pD * fd45.x;
        acc[5] += pA * fa45.y + pB * fb45.y + pC * fc45.y + pD * fd45.y;
        acc[6] += pA * fa67.x + pB * fb67.x + pC * fc67.x + pD * fd67.x;
        acc[7] += pA * fa67.y + pB * fb67.y + pC * fc67.y + pD * fd67.y;
    }
    for (; j < e1; j += 16) {
        int s = bdata[j];
        uint4 hv = rec1[s];
        float2 f01 = unpack2h(hv.x), f23 = unpack2h(hv.y);
        float2 f45 = unpack2h(hv.z), f67 = unpack2h(hv.w);
        float ss = f01.x*as0 + f01.y*as1 + f23.x*as2 + f23.y*as3
                 + f45.x*as4 + f45.y*as5 + f67.x*as6 + f67.y*as7;
        float e = ss + sdvn;
        e = (e > 0.f) ? e : NEG_SLOPE * e;
        float p = __expf(e - SHIFT1);
        z += p;
        acc[0] += p * f01.x; acc[1] += p * f01.y;
        acc[2] += p * f23.x; acc[3] += p * f23.y;
        acc[4] += p * f45.x; acc[5] += p * f45.y;
        acc[6] += p * f67.x; acc[7] += p * f67.y;
    }

#pragma unroll
    for (int off = 1; off < 16; off <<= 1) {
        z += __shfl_xor(z, off);
#pragma unroll
        for (int f = 0; f < HID; ++f) acc[f] += __shfl_xor(acc[f], off);
    }

    if (q == 0) {
        float inv = 1.f / (z + 1e-16f);
        float c0 = 0.f, c1 = 0.f;
#pragma unroll
        for (int f = 0; f < HID; ++f) {
            float hr = fmaxf(acc[f] * inv + b1[f], 0.f);
            c0 = fmaf(hr, W2[f * NCLS + 0], c0);
            c1 = fmaf(hr, W2[f * NCLS + 1], c1);
        }
        rec2[n] = make_float2(c0, c1);
    }
}

// ---------------- KAgg2: layer-2 agg, ONE float2 gather per edge -----------
__global__ __launch_bounds__(256) void kAgg2(
    const int* __restrict__ nptr, const unsigned int* __restrict__ bdata,
    const float2* __restrict__ rec2,
    const float* __restrict__ a2s, const float* __restrict__ a2d,
    const float* __restrict__ b2, float* __restrict__ out)
{
    int gi = blockIdx.x * 256 + threadIdx.x;
    int n = gi >> 4, q = gi & 15;
    if (n >= N_NODES) return;

    float ws0 = a2s[0], ws1 = a2s[1];
    float wd0 = a2d[0], wd1 = a2d[1];

    int e0 = nptr[n], e1 = nptr[n + 1];
    float2 rn = rec2[n];
    float sdvn = rn.x * wd0 + rn.y * wd1;
    float z = 0.f, a0 = 0.f, a1 = 0.f;

    int j = e0 + q;
    for (; j + 48 < e1; j += 64) {
        int sA = bdata[j];
        int sB = bdata[j + 16];
        int sC = bdata[j + 32];
        int sD = bdata[j + 48];
        float2 rA = rec2[sA];
        float2 rB = rec2[sB];
        float2 rC = rec2[sC];
        float2 rD = rec2[sD];
        float eA = rA.x * ws0 + rA.y * ws1 + sdvn; eA = (eA > 0.f) ? eA : NEG_SLOPE * eA;
        float eB = rB.x * ws0 + rB.y * ws1 + sdvn; eB = (eB > 0.f) ? eB : NEG_SLOPE * eB;
        float eC = rC.x * ws0 + rC.y * ws1 + sdvn; eC = (eC > 0.f) ? eC : NEG_SLOPE * eC;
        float eD = rD.x * ws0 + rD.y * ws1 + sdvn; eD = (eD > 0.f) ? eD : NEG_SLOPE * eD;
        float pA = __expf(eA - SHIFT2);
        float pB = __expf(eB - SHIFT2);
        float pC = __expf(eC - SHIFT2);
        float pD = __expf(eD - SHIFT2);
        z += (pA + pB) + (pC + pD);
        a0 += pA * rA.x + pB * rB.x + pC * rC.x + pD * rD.x;
        a1 += pA * rA.y + pB * rB.y + pC * rC.y + pD * rD.y;
    }
    for (; j < e1; j += 16) {
        int s = bdata[j];
        float2 r = rec2[s];
        float e = r.x * ws0 + r.y * ws1 + sdvn;
        e = (e > 0.f) ? e : NEG_SLOPE * e;
        float p = __expf(e - SHIFT2);
        z += p; a0 += p * r.x; a1 += p * r.y;
    }

#pragma unroll
    for (int off = 1; off < 16; off <<= 1) {
        z  += __shfl_xor(z, off);
        a0 += __shfl_xor(a0, off);
        a1 += __shfl_xor(a1, off);
    }

    if (q == 0) {
        float inv = 1.f / (z + 1e-16f);
        float o0 = a0 * inv + b2[0];
        float o1 = a1 * inv + b2[1];
        float mx = fmaxf(o0, o1);
        float lse = mx + __logf(__expf(o0 - mx) + __expf(o1 - mx));
        ((float2*)out)[n] = make_float2(o0 - lse, o1 - lse);
    }
}

// ---------------- host launch ----------------------------------------------
extern "C" void kernel_launch(void* const* d_in, const int* in_sizes, int n_in,
                              void* d_out, int out_size, void* d_ws, size_t ws_size,
                              hipStream_t stream) {
    const float* x   = (const float*)d_in[0];
    const float* W1  = (const float*)d_in[1];
    const float* a1s = (const float*)d_in[2];
    const float* a1d = (const float*)d_in[3];
    const float* b1  = (const float*)d_in[4];
    const float* W2  = (const float*)d_in[5];
    const float* a2s = (const float*)d_in[6];
    const float* a2d = (const float*)d_in[7];
    const float* b2  = (const float*)d_in[8];
    const int*   ei  = (const int*)d_in[9];
    const int* src = ei;
    const int* dst = ei + N_EDGES;

    char* ws = (char*)d_ws;
    uint4*  rec1  = (uint4*) (ws + 0);              // 1,600,000 (100000 x 16B)
    float*  s1d   = (float*) (ws + 1600000);        //   400,000
    float2* rec2  = (float2*)(ws + 2000000);        //   800,000
    int*    nptr  = (int*)   (ws + 2800000);        //   400,016
    int*    cbase = (int*)   (ws + 3200064);        //     1,568 -> pad
    int*    tot   = (int*)   (ws + 3201664);        //     1,564 -> pad
    unsigned int* bdata = (unsigned int*)(ws + 3203264);  // 25,600,000 -> ends 28,803,264
    int*    gcnt  = (int*)   (ws + 28803264);       // 782x391x4 = 1,223,048
    int*    lpre  = (int*)   (ws + 30026312);       // 391x782x4 = 1,223,048 -> ends 31,249,360

    float* out = (float*)d_out;

    k0_node<<<(N_NODES + 255) / 256, 256, 0, stream>>>(x, W1, a1d, rec1, s1d);
    kH_hist<<<NSTG, 256, 0, stream>>>(dst, gcnt);
    kS_scan<<<NBC, 256, 0, stream>>>(gcnt, lpre, tot);
    k2b_cscan<<<1, 512, 0, stream>>>(tot, cbase);
    kA_stage<<<NSTG, 1024, 0, stream>>>(src, dst, cbase, lpre, bdata);
    kB_sort<<<NBC, 1024, 0, stream>>>(cbase, bdata, nptr);
    kAgg1<<<(N_NODES * 16 + 255) / 256, 256, 0, stream>>>(nptr, bdata, rec1, s1d, a1s,
                                                          b1, W2, rec2);
    kAgg2<<<(N_NODES * 16 + 255) / 256, 256, 0, stream>>>(nptr, bdata, rec2,
                                                          a2s, a2d, b2, out);
}

// Round 19
// 132.467 us; speedup vs baseline: 1.5773x; 1.1095x over previous
//
#include <hip/hip_runtime.h>
#include <hip/hip_fp16.h>
#include <math.h>

#define N_NODES 100000
#define N_EDGES 6400000
#define F_IN 36
#define HID 8
#define NCLS 2
#define NEG_SLOPE 0.2f

#define COARSE 256                        // nodes per coarse bucket (dst >> 8)
#define NBC 391                           // ceil(N_NODES/256)
#define CAPC 18432                        // max edges per coarse bucket
#define CHUNK 8192                        // edges per scatter chunk
#define NSTG ((N_EDGES + CHUNK - 1) / CHUNK)   // 782
#define SHIFT1 8.0f                       // softmax shift (softmax is shift-invariant)
#define SHIFT2 16.0f

static __device__ __forceinline__ unsigned pack2h(float a, float b) {
    __half2 h = __float22half2_rn(make_float2(a, b));
    return *reinterpret_cast<unsigned*>(&h);
}
static __device__ __forceinline__ float2 unpack2h(unsigned u) {
    __half2 h = *reinterpret_cast<__half2*>(&u);
    return __half22float2(h);
}

// ------- K0: per-node rec1 (fp16 h) + s1d (no histogram) -------------------
__global__ __launch_bounds__(256) void k0_node(
    const float* __restrict__ x, const float* __restrict__ W1,
    const float* __restrict__ a1d_g,
    uint4* __restrict__ rec1, float* __restrict__ s1d)
{
    __shared__ float sW[F_IN * HID];
    __shared__ float sad[HID];
    int tid = threadIdx.x;
    for (int i = tid; i < F_IN * HID; i += 256) sW[i] = W1[i];
    if (tid < HID) sad[tid] = a1d_g[tid];
    __syncthreads();

    int n = blockIdx.x * 256 + tid;
    if (n >= N_NODES) return;

    const float4* xp = (const float4*)(x + (size_t)n * F_IN);
    float h[HID];
#pragma unroll
    for (int f = 0; f < HID; ++f) h[f] = 0.f;
#pragma unroll
    for (int q = 0; q < F_IN / 4; ++q) {
        float4 v = xp[q];
        float vs[4] = {v.x, v.y, v.z, v.w};
#pragma unroll
        for (int j = 0; j < 4; ++j) {
            int k = q * 4 + j;
#pragma unroll
            for (int f = 0; f < HID; ++f) h[f] = fmaf(vs[j], sW[k * HID + f], h[f]);
        }
    }
    float sd = 0.f;
#pragma unroll
    for (int f = 0; f < HID; ++f) sd = fmaf(h[f], sad[f], sd);

    uint4 w;
    w.x = pack2h(h[0], h[1]);
    w.y = pack2h(h[2], h[3]);
    w.z = pack2h(h[4], h[5]);
    w.w = pack2h(h[6], h[7]);
    rec1[n] = w;
    s1d[n] = sd;
}

// ------- KH: per-chunk bucket histogram -> gcnt[g][b] (coalesced) ----------
__global__ __launch_bounds__(256) void kH_hist(const int* __restrict__ dst,
                                               int* __restrict__ gcnt)
{
    __shared__ int lh[NBC];
    int tid = threadIdx.x, g = blockIdx.x;
    for (int i = tid; i < NBC; i += 256) lh[i] = 0;
    __syncthreads();

    int e0 = g * CHUNK;
    int ne = N_EDGES - e0; if (ne > CHUNK) ne = CHUNK;
    int n4 = ne >> 2;
    const int4* dv = (const int4*)(dst + e0);
    for (int i = tid; i < n4; i += 256) {
        int4 d = dv[i];
        atomicAdd(&lh[d.x >> 8], 1);
        atomicAdd(&lh[d.y >> 8], 1);
        atomicAdd(&lh[d.z >> 8], 1);
        atomicAdd(&lh[d.w >> 8], 1);
    }
    __syncthreads();
    for (int i = tid; i < NBC; i += 256) gcnt[(size_t)g * NBC + i] = lh[i];
}

// ------- KS: per-bucket exclusive scan over chunks -> lpre[b][g], tot[b] ---
__global__ __launch_bounds__(256) void kS_scan(const int* __restrict__ gcnt,
                                               int* __restrict__ lpre, int* __restrict__ tot)
{
    __shared__ int sv[256];
    int b = blockIdx.x, tid = threadIdx.x;
    int carry = 0;
    const int ntile = (NSTG + 255) / 256;
    for (int t = 0; t < ntile; ++t) {
        int g = t * 256 + tid;
        int v = (g < NSTG) ? gcnt[(size_t)g * NBC + b] : 0;
        sv[tid] = v;
        __syncthreads();
        for (int off = 1; off < 256; off <<= 1) {
            int x = (tid >= off) ? sv[tid - off] : 0;
            __syncthreads();
            sv[tid] += x;
            __syncthreads();
        }
        if (g < NSTG) lpre[(size_t)b * NSTG + g] = carry + sv[tid] - v;
        carry += sv[255];
        __syncthreads();
    }
    if (tid == 0) tot[b] = carry;
}

// ------- K2b: scan bucket totals -> cbase ----------------------------------
__global__ __launch_bounds__(512) void k2b_cscan(const int* __restrict__ tot,
                                                 int* __restrict__ cbase)
{
    __shared__ int s[512];
    int tid = threadIdx.x;
    int v = (tid < NBC) ? tot[tid] : 0;
    s[tid] = v;
    __syncthreads();
    for (int off = 1; off < 512; off <<= 1) {
        int t = (tid >= off) ? s[tid - off] : 0;
        __syncthreads();
        s[tid] += t;
        __syncthreads();
    }
    int ex = s[tid] - v;
    if (tid < NBC) cbase[tid] = ex;
    if (tid == NBC) cbase[NBC] = ex;   // == N_EDGES
}

// ------- KA: staged scatter — NO global atomics (precomputed offsets) ------
__global__ __launch_bounds__(1024) void kA_stage(
    const int* __restrict__ src, const int* __restrict__ dst,
    const int* __restrict__ cbase, const int* __restrict__ lpre,
    unsigned int* __restrict__ bdata)
{
    __shared__ unsigned int stg[CHUNK];          // 32 KB
    __shared__ unsigned short aux[CHUNK];        // 16 KB
    __shared__ int lh[NBC];
    __shared__ int lstart[NBC];
    __shared__ int lcur[NBC];
    __shared__ int tbase[NBC];
    int tid = threadIdx.x, g = blockIdx.x;

    for (int i = tid; i < NBC; i += 1024) lh[i] = 0;
    __syncthreads();

    int e0 = g * CHUNK;
    int ne = N_EDGES - e0; if (ne > CHUNK) ne = CHUNK;   // multiple of 4
    int n4 = ne >> 2;
    const int4* dv = (const int4*)(dst + e0);
    const int4* sv = (const int4*)(src + e0);

    // pass 1: load chunk into registers + histogram (2 int4 per thread)
    int4 d0, s0, d1, s1;
    bool v0 = (tid < n4), v1 = (tid + 1024 < n4);
    if (v0) {
        d0 = dv[tid]; s0 = sv[tid];
        atomicAdd(&lh[d0.x >> 8], 1);
        atomicAdd(&lh[d0.y >> 8], 1);
        atomicAdd(&lh[d0.z >> 8], 1);
        atomicAdd(&lh[d0.w >> 8], 1);
    }
    if (v1) {
        d1 = dv[tid + 1024]; s1 = sv[tid + 1024];
        atomicAdd(&lh[d1.x >> 8], 1);
        atomicAdd(&lh[d1.y >> 8], 1);
        atomicAdd(&lh[d1.z >> 8], 1);
        atomicAdd(&lh[d1.w >> 8], 1);
    }
    __syncthreads();

    // wave-0 exclusive scan of 391 counts (7 per lane)
    if (tid < 64) {
        int base = tid * 7;
        int cnt[7];
        int s = 0;
#pragma unroll
        for (int k = 0; k < 7; ++k) {
            int b = base + k;
            cnt[k] = (b < NBC) ? lh[b] : 0;
            s += cnt[k];
        }
        int inc = s;
#pragma unroll
        for (int off = 1; off < 64; off <<= 1) {
            int t2 = __shfl_up(inc, off);
            if (tid >= off) inc += t2;
        }
        int ex = inc - s;
#pragma unroll
        for (int k = 0; k < 7; ++k) {
            int b = base + k;
            if (b < NBC) { lstart[b] = ex; lcur[b] = ex; ex += cnt[k]; }
        }
    }
    __syncthreads();

    // global offsets: plain loads, zero atomics
    for (int b = tid; b < NBC; b += 1024) {
        tbase[b] = cbase[b] + lpre[(size_t)b * NSTG + g];
    }

    // pass 2: scatter registers into LDS bucket order (+ record bucket id)
    if (v0) {
        int b, p;
        b = d0.x >> 8; p = atomicAdd(&lcur[b], 1); stg[p] = (unsigned)s0.x | ((unsigned)(d0.x & 255) << 17); aux[p] = (unsigned short)b;
        b = d0.y >> 8; p = atomicAdd(&lcur[b], 1); stg[p] = (unsigned)s0.y | ((unsigned)(d0.y & 255) << 17); aux[p] = (unsigned short)b;
        b = d0.z >> 8; p = atomicAdd(&lcur[b], 1); stg[p] = (unsigned)s0.z | ((unsigned)(d0.z & 255) << 17); aux[p] = (unsigned short)b;
        b = d0.w >> 8; p = atomicAdd(&lcur[b], 1); stg[p] = (unsigned)s0.w | ((unsigned)(d0.w & 255) << 17); aux[p] = (unsigned short)b;
    }
    if (v1) {
        int b, p;
        b = d1.x >> 8; p = atomicAdd(&lcur[b], 1); stg[p] = (unsigned)s1.x | ((unsigned)(d1.x & 255) << 17); aux[p] = (unsigned short)b;
        b = d1.y >> 8; p = atomicAdd(&lcur[b], 1); stg[p] = (unsigned)s1.y | ((unsigned)(d1.y & 255) << 17); aux[p] = (unsigned short)b;
        b = d1.z >> 8; p = atomicAdd(&lcur[b], 1); stg[p] = (unsigned)s1.z | ((unsigned)(d1.z & 255) << 17); aux[p] = (unsigned short)b;
        b = d1.w >> 8; p = atomicAdd(&lcur[b], 1); stg[p] = (unsigned)s1.w | ((unsigned)(d1.w & 255) << 17); aux[p] = (unsigned short)b;
    }
    __syncthreads();

    // flush: every lane active; runs stay contiguous -> coalesced
    for (int i = tid; i < ne; i += 1024) {
        int bb = aux[i];
        bdata[tbase[bb] + (i - lstart[bb])] = stg[i];
    }
}

// ------- KB: LDS->LDS node sort, coalesced writeback (1024T) ---------------
__global__ __launch_bounds__(1024) void kB_sort(
    const int* __restrict__ cbase, unsigned int* __restrict__ bdata,
    int* __restrict__ nptr)
{
    __shared__ unsigned int raw[CAPC];    // 72 KB
    __shared__ unsigned int srt[CAPC];    // 72 KB
    __shared__ int cnt[COARSE];
    __shared__ int sstart[COARSE];
    __shared__ int cur[COARSE];
    int tid = threadIdx.x;
    int c = blockIdx.x;
    int cb0 = cbase[c], cb1 = cbase[c + 1];
    int ne = cb1 - cb0;

    if (tid < COARSE) cnt[tid] = 0;
    __syncthreads();

    for (int i = tid; i < ne; i += 1024) {
        unsigned pk = bdata[cb0 + i];
        raw[i] = pk;
        atomicAdd(&cnt[pk >> 17], 1);
    }
    __syncthreads();

    if (tid < 64) {
        int base = tid * 4;
        int c0 = cnt[base], c1 = cnt[base + 1], c2 = cnt[base + 2], c3 = cnt[base + 3];
        int s = c0 + c1 + c2 + c3;
        int inc = s;
#pragma unroll
        for (int off = 1; off < 64; off <<= 1) {
            int t2 = __shfl_up(inc, off);
            if (tid >= off) inc += t2;
        }
        int ex = inc - s;
        sstart[base]     = ex; cur[base]     = ex; ex += c0;
        sstart[base + 1] = ex; cur[base + 1] = ex; ex += c1;
        sstart[base + 2] = ex; cur[base + 2] = ex; ex += c2;
        sstart[base + 3] = ex; cur[base + 3] = ex;
    }
    __syncthreads();

    if (tid < COARSE) {
        int nid = c * COARSE + tid;
        if (nid < N_NODES) nptr[nid] = cb0 + sstart[tid];
    }
    if (c == 0 && tid == 0) nptr[N_NODES] = N_EDGES;

    // LDS->LDS counting-sort scatter (scatter stays on-chip)
    for (int i = tid; i < ne; i += 1024) {
        unsigned pk = raw[i];
        int p = atomicAdd(&cur[pk >> 17], 1);
        srt[p] = pk & 0x1FFFF;
    }
    __syncthreads();

    // coalesced global writeback
    for (int i = tid; i < ne; i += 1024) bdata[cb0 + i] = srt[i];
}

// ---------------- KAgg1: layer-1 agg, ONE uint4 gather per edge ------------
__global__ __launch_bounds__(256) void kAgg1(
    const int* __restrict__ nptr, const unsigned int* __restrict__ bdata,
    const uint4* __restrict__ rec1, const float* __restrict__ s1d,
    const float* __restrict__ a1s_g,
    const float* __restrict__ b1, const float* __restrict__ W2,
    float2* __restrict__ rec2)
{
    int gi = blockIdx.x * 256 + threadIdx.x;
    int n = gi >> 4, q = gi & 15;
    if (n >= N_NODES) return;

    float as0 = a1s_g[0], as1 = a1s_g[1], as2 = a1s_g[2], as3 = a1s_g[3];
    float as4 = a1s_g[4], as5 = a1s_g[5], as6 = a1s_g[6], as7 = a1s_g[7];

    int e0 = nptr[n], e1 = nptr[n + 1];
    float sdvn = s1d[n];
    float z = 0.f;
    float acc[HID];
#pragma unroll
    for (int f = 0; f < HID; ++f) acc[f] = 0.f;

    int j = e0 + q;
    for (; j + 48 < e1; j += 64) {
        int sA = bdata[j], sB = bdata[j + 16], sC = bdata[j + 32], sD = bdata[j + 48];
        uint4 ha = rec1[sA];
        uint4 hb = rec1[sB];
        uint4 hc = rec1[sC];
        uint4 hd = rec1[sD];
        float2 fa01 = unpack2h(ha.x), fa23 = unpack2h(ha.y), fa45 = unpack2h(ha.z), fa67 = unpack2h(ha.w);
        float2 fb01 = unpack2h(hb.x), fb23 = unpack2h(hb.y), fb45 = unpack2h(hb.z), fb67 = unpack2h(hb.w);
        float2 fc01 = unpack2h(hc.x), fc23 = unpack2h(hc.y), fc45 = unpack2h(hc.z), fc67 = unpack2h(hc.w);
        float2 fd01 = unpack2h(hd.x), fd23 = unpack2h(hd.y), fd45 = unpack2h(hd.z), fd67 = unpack2h(hd.w);
        float ssA = fa01.x*as0 + fa01.y*as1 + fa23.x*as2 + fa23.y*as3
                  + fa45.x*as4 + fa45.y*as5 + fa67.x*as6 + fa67.y*as7;
        float ssB = fb01.x*as0 + fb01.y*as1 + fb23.x*as2 + fb23.y*as3
                  + fb45.x*as4 + fb45.y*as5 + fb67.x*as6 + fb67.y*as7;
        float ssC = fc01.x*as0 + fc01.y*as1 + fc23.x*as2 + fc23.y*as3
                  + fc45.x*as4 + fc45.y*as5 + fc67.x*as6 + fc67.y*as7;
        float ssD = fd01.x*as0 + fd01.y*as1 + fd23.x*as2 + fd23.y*as3
                  + fd45.x*as4 + fd45.y*as5 + fd67.x*as6 + fd67.y*as7;
        float eA = ssA + sdvn; eA = (eA > 0.f) ? eA : NEG_SLOPE * eA;
        float eB = ssB + sdvn; eB = (eB > 0.f) ? eB : NEG_SLOPE * eB;
        float eC = ssC + sdvn; eC = (eC > 0.f) ? eC : NEG_SLOPE * eC;
        float eD = ssD + sdvn; eD = (eD > 0.f) ? eD : NEG_SLOPE * eD;
        float pA = __expf(eA - SHIFT1);
        float pB = __expf(eB - SHIFT1);
        float pC = __expf(eC - SHIFT1);
        float pD = __expf(eD - SHIFT1);
        z += (pA + pB) + (pC + pD);
        acc[0] += pA * fa01.x + pB * fb01.x + pC * fc01.x + pD * fd01.x;
        acc[1] += pA * fa01.y + pB * fb01.y + pC * fc01.y + pD * fd01.y;
        acc[2] += pA * fa23.x + pB * fb23.x + pC * fc23.x + pD * fd23.x;
        acc[3] += pA * fa23.y + pB * fb23.y + pC * fc23.y + pD * fd23.y;
        acc[4] += pA * fa45.x + pB * fb45.x + pC * fc45.x + pD * fd45.x;
        acc[5] += pA * fa45.y + pB * fb45.y + pC * fc45.y + pD * fd45.y;
        acc[6] += pA * fa67.x + pB * fb67.x + pC * fc67.x + pD * fd67.x;
        acc[7] += pA * fa67.y + pB * fb67.y + pC * fc67.y + pD * fd67.y;
    }
    for (; j < e1; j += 16) {
        int s = bdata[j];
        uint4 hv = rec1[s];
        float2 f01 = unpack2h(hv.x), f23 = unpack2h(hv.y);
        float2 f45 = unpack2h(hv.z), f67 = unpack2h(hv.w);
        float ss = f01.x*as0 + f01.y*as1 + f23.x*as2 + f23.y*as3
                 + f45.x*as4 + f45.y*as5 + f67.x*as6 + f67.y*as7;
        float e = ss + sdvn;
        e = (e > 0.f) ? e : NEG_SLOPE * e;
        float p = __expf(e - SHIFT1);
        z += p;
        acc[0] += p * f01.x; acc[1] += p * f01.y;
        acc[2] += p * f23.x; acc[3] += p * f23.y;
        acc[4] += p * f45.x; acc[5] += p * f45.y;
        acc[6] += p * f67.x; acc[7] += p * f67.y;
    }

#pragma unroll
    for (int off = 1; off < 16; off <<= 1) {
        z += __shfl_xor(z, off);
#pragma unroll
        for (int f = 0; f < HID; ++f) acc[f] += __shfl_xor(acc[f], off);
    }

    if (q == 0) {
        float inv = 1.f / (z + 1e-16f);
        float c0 = 0.f, c1 = 0.f;
#pragma unroll
        for (int f = 0; f < HID; ++f) {
            float hr = fmaxf(acc[f] * inv + b1[f], 0.f);
            c0 = fmaf(hr, W2[f * NCLS + 0], c0);
            c1 = fmaf(hr, W2[f * NCLS + 1], c1);
        }
        rec2[n] = make_float2(c0, c1);
    }
}

// ---------------- KAgg2: layer-2 agg, ONE float2 gather per edge -----------
__global__ __launch_bounds__(256) void kAgg2(
    const int* __restrict__ nptr, const unsigned int* __restrict__ bdata,
    const float2* __restrict__ rec2,
    const float* __restrict__ a2s, const float* __restrict__ a2d,
    const float* __restrict__ b2, float* __restrict__ out)
{
    int gi = blockIdx.x * 256 + threadIdx.x;
    int n = gi >> 4, q = gi & 15;
    if (n >= N_NODES) return;

    float ws0 = a2s[0], ws1 = a2s[1];
    float wd0 = a2d[0], wd1 = a2d[1];

    int e0 = nptr[n], e1 = nptr[n + 1];
    float2 rn = rec2[n];
    float sdvn = rn.x * wd0 + rn.y * wd1;
    float z = 0.f, a0 = 0.f, a1 = 0.f;

    int j = e0 + q;
    for (; j + 48 < e1; j += 64) {
        int sA = bdata[j];
        int sB = bdata[j + 16];
        int sC = bdata[j + 32];
        int sD = bdata[j + 48];
        float2 rA = rec2[sA];
        float2 rB = rec2[sB];
        float2 rC = rec2[sC];
        float2 rD = rec2[sD];
        float eA = rA.x * ws0 + rA.y * ws1 + sdvn; eA = (eA > 0.f) ? eA : NEG_SLOPE * eA;
        float eB = rB.x * ws0 + rB.y * ws1 + sdvn; eB = (eB > 0.f) ? eB : NEG_SLOPE * eB;
        float eC = rC.x * ws0 + rC.y * ws1 + sdvn; eC = (eC > 0.f) ? eC : NEG_SLOPE * eC;
        float eD = rD.x * ws0 + rD.y * ws1 + sdvn; eD = (eD > 0.f) ? eD : NEG_SLOPE * eD;
        float pA = __expf(eA - SHIFT2);
        float pB = __expf(eB - SHIFT2);
        float pC = __expf(eC - SHIFT2);
        float pD = __expf(eD - SHIFT2);
        z += (pA + pB) + (pC + pD);
        a0 += pA * rA.x + pB * rB.x + pC * rC.x + pD * rD.x;
        a1 += pA * rA.y + pB * rB.y + pC * rC.y + pD * rD.y;
    }
    for (; j < e1; j += 16) {
        int s = bdata[j];
        float2 r = rec2[s];
        float e = r.x * ws0 + r.y * ws1 + sdvn;
        e = (e > 0.f) ? e : NEG_SLOPE * e;
        float p = __expf(e - SHIFT2);
        z += p; a0 += p * r.x; a1 += p * r.y;
    }

#pragma unroll
    for (int off = 1; off < 16; off <<= 1) {
        z  += __shfl_xor(z, off);
        a0 += __shfl_xor(a0, off);
        a1 += __shfl_xor(a1, off);
    }

    if (q == 0) {
        float inv = 1.f / (z + 1e-16f);
        float o0 = a0 * inv + b2[0];
        float o1 = a1 * inv + b2[1];
        float mx = fmaxf(o0, o1);
        float lse = mx + __logf(__expf(o0 - mx) + __expf(o1 - mx));
        ((float2*)out)[n] = make_float2(o0 - lse, o1 - lse);
    }
}

// ---------------- host launch ----------------------------------------------
extern "C" void kernel_launch(void* const* d_in, const int* in_sizes, int n_in,
                              void* d_out, int out_size, void* d_ws, size_t ws_size,
                              hipStream_t stream) {
    const float* x   = (const float*)d_in[0];
    const float* W1  = (const float*)d_in[1];
    const float* a1s = (const float*)d_in[2];
    const float* a1d = (const float*)d_in[3];
    const float* b1  = (const float*)d_in[4];
    const float* W2  = (const float*)d_in[5];
    const float* a2s = (const float*)d_in[6];
    const float* a2d = (const float*)d_in[7];
    const float* b2  = (const float*)d_in[8];
    const int*   ei  = (const int*)d_in[9];
    const int* src = ei;
    const int* dst = ei + N_EDGES;

    char* ws = (char*)d_ws;
    uint4*  rec1  = (uint4*) (ws + 0);              // 1,600,000 (100000 x 16B)
    float*  s1d   = (float*) (ws + 1600000);        //   400,000
    float2* rec2  = (float2*)(ws + 2000000);        //   800,000
    int*    nptr  = (int*)   (ws + 2800000);        //   400,016
    int*    cbase = (int*)   (ws + 3200064);        //     1,568 -> pad
    int*    tot   = (int*)   (ws + 3201664);        //     1,564 -> pad
    unsigned int* bdata = (unsigned int*)(ws + 3203264);  // 25,600,000 -> ends 28,803,264
    int*    gcnt  = (int*)   (ws + 28803264);       // 782x391x4 = 1,223,048
    int*    lpre  = (int*)   (ws + 30026312);       // 391x782x4 = 1,223,048 -> ends 31,249,360

    float* out = (float*)d_out;

    k0_node<<<(N_NODES + 255) / 256, 256, 0, stream>>>(x, W1, a1d, rec1, s1d);
    kH_hist<<<NSTG, 256, 0, stream>>>(dst, gcnt);
    kS_scan<<<NBC, 256, 0, stream>>>(gcnt, lpre, tot);
    k2b_cscan<<<1, 512, 0, stream>>>(tot, cbase);
    kA_stage<<<NSTG, 1024, 0, stream>>>(src, dst, cbase, lpre, bdata);
    kB_sort<<<NBC, 1024, 0, stream>>>(cbase, bdata, nptr);
    kAgg1<<<(N_NODES * 16 + 255) / 256, 256, 0, stream>>>(nptr, bdata, rec1, s1d, a1s,
                                                          b1, W2, rec2);
    kAgg2<<<(N_NODES * 16 + 255) / 256, 256, 0, stream>>>(nptr, bdata, rec2,
                                                          a2s, a2d, b2, out);
}